// Round 1
// baseline (2800.221 us; speedup 1.0000x reference)
//
#include <hip/hip_runtime.h>
#include <cstdint>
#include <cstddef>

#define N_NODES 200000
#define N_EDGES 6400000
#define NB      64
#define MROWS   8192     // NB*ROWS
#define FEAT    2560

// ---------------------------------------------------------------------------
// Workspace layout (floats):
//   z     [N]          @ 0
//   agg   [N*6]        @ 200000
//   gsum  [64*4]       @ 1400000
//   gcnt  [64]         @ 1400256
//   --- memset span ends at 1400320 ---
//   xl    [N*8]        @ 1400320   (padded stride 8 for aligned gathers)
//   xr    [N*8]        @ 3000320
//   f1    [8192*256]   @ 4600320
//   f2    [8192*64]    @ 6697472
//   f3    [8192*8]     @ 7221760
//   xf    [64*32]      @ 7287296
// total 7,289,344 floats = 29.2 MB
// ---------------------------------------------------------------------------

// xl = x@W_l + b_l, xr = x@W_r + b_r.  16 lanes per node; W rows live in
// registers (48 floats/lane/matrix, contiguous 192B chunk -> 12 float4 loads).
__global__ __launch_bounds__(256) void node_xform(
    const float* __restrict__ x,
    const float* __restrict__ Wl, const float* __restrict__ bl,
    const float* __restrict__ Wr, const float* __restrict__ br,
    float* __restrict__ xl, float* __restrict__ xr)
{
    const int t = threadIdx.x;
    const int l = t & 15;
    const int node = blockIdx.x * 16 + (t >> 4);

    float wl[48], wr[48];
#pragma unroll
    for (int q = 0; q < 12; q++) {
        *(float4*)&wl[q * 4] = *(const float4*)(Wl + 48 * l + 4 * q);
        *(float4*)&wr[q * 4] = *(const float4*)(Wr + 48 * l + 4 * q);
    }
    float xv[8];
    *(float4*)&xv[0] = *(const float4*)(x + (size_t)node * 128 + l * 8);
    *(float4*)&xv[4] = *(const float4*)(x + (size_t)node * 128 + l * 8 + 4);

    float al[6] = {}, ar[6] = {};
#pragma unroll
    for (int i = 0; i < 8; i++) {
#pragma unroll
        for (int j = 0; j < 6; j++) {
            al[j] += xv[i] * wl[i * 6 + j];
            ar[j] += xv[i] * wr[i * 6 + j];
        }
    }
#pragma unroll
    for (int off = 8; off >= 1; off >>= 1) {
#pragma unroll
        for (int j = 0; j < 6; j++) {
            al[j] += __shfl_xor(al[j], off);
            ar[j] += __shfl_xor(ar[j], off);
        }
    }
    if (l == 0) {
#pragma unroll
        for (int j = 0; j < 6; j++) {
            xl[(size_t)node * 8 + j] = al[j] + bl[j];
            xr[(size_t)node * 8 + j] = ar[j] + br[j];
        }
    }
}

// One pass over E + N self-loop edges: p = exp(att . leaky(xl[s]+xr[d], 0.2));
// z[d] += p; agg[d] += p*xl[s].  (max-subtraction skipped: scores bounded ~7,
// exp safe in fp32, alpha = p/z unchanged.)
__global__ __launch_bounds__(256) void edge_attn(
    const int* __restrict__ ei,
    const float* __restrict__ xl, const float* __restrict__ xr,
    const float* __restrict__ att,
    float* __restrict__ z, float* __restrict__ agg)
{
    const int t = blockIdx.x * 256 + threadIdx.x;
    if (t >= N_EDGES + N_NODES) return;
    int s, d;
    if (t < N_EDGES) { s = ei[t]; d = ei[N_EDGES + t]; }
    else             { s = d = t - N_EDGES; }

    float4 s0 = *(const float4*)(xl + (size_t)s * 8);
    float2 s1 = *(const float2*)(xl + (size_t)s * 8 + 4);
    float4 d0 = *(const float4*)(xr + (size_t)d * 8);
    float2 d1 = *(const float2*)(xr + (size_t)d * 8 + 4);
    float xls[6] = {s0.x, s0.y, s0.z, s0.w, s1.x, s1.y};
    float xrd[6] = {d0.x, d0.y, d0.z, d0.w, d1.x, d1.y};

    float sc = 0.f;
#pragma unroll
    for (int j = 0; j < 6; j++) {
        float v = xls[j] + xrd[j];
        v = (v >= 0.f) ? v : 0.2f * v;
        sc += att[j] * v;
    }
    const float p = __expf(sc);
    atomicAdd(z + d, p);
#pragma unroll
    for (int j = 0; j < 6; j++)
        atomicAdd(agg + (size_t)d * 6 + j, p * xls[j]);
}

// x1 = leaky(agg/z + conv_b, .01); h = x1@jk_W + jk_b; segment-sum h by batch.
// batch is sorted -> almost every wave is single-graph: shfl-reduce, 5 atomics/wave.
__global__ __launch_bounds__(256) void finalize_pool(
    const float* __restrict__ agg, const float* __restrict__ z,
    const float* __restrict__ conv_b,
    const float* __restrict__ jkW, const float* __restrict__ jkb,
    const int* __restrict__ batch,
    float* __restrict__ gsum, float* __restrict__ gcnt)
{
    const int t = blockIdx.x * 256 + threadIdx.x;
    if (t >= N_NODES) return;   // N%64==0: whole waves exit, shfl below is safe
    const float zz = z[t];
    float h[4] = {jkb[0], jkb[1], jkb[2], jkb[3]};
#pragma unroll
    for (int j = 0; j < 6; j++) {
        float a = agg[(size_t)t * 6 + j] / zz + conv_b[j];
        a = (a >= 0.f) ? a : 0.01f * a;
#pragma unroll
        for (int c = 0; c < 4; c++) h[c] += a * jkW[j * 4 + c];
    }
    const int b = batch[t];
    const int b0 = __shfl(b, 0);
    if (__all(b == b0)) {
#pragma unroll
        for (int off = 32; off >= 1; off >>= 1)
#pragma unroll
            for (int c = 0; c < 4; c++) h[c] += __shfl_xor(h[c], off);
        if ((threadIdx.x & 63) == 0) {
#pragma unroll
            for (int c = 0; c < 4; c++) atomicAdd(gsum + b * 4 + c, h[c]);
            atomicAdd(gcnt + b, 64.f);
        }
    } else {
#pragma unroll
        for (int c = 0; c < 4; c++) atomicAdd(gsum + b * 4 + c, h[c]);
        atomicAdd(gcnt + b, 1.f);
    }
}

// C[M,N] = A[M,K] @ B[K,N] + bias.  64x64 tile, BK=32, 256 threads, 4x4/thread.
__global__ __launch_bounds__(256) void gemm64(
    const float* __restrict__ A, const float* __restrict__ B,
    const float* __restrict__ bias, float* __restrict__ C,
    int M, int N, int K)
{
    __shared__ float As[32][68];   // [k][m], padded
    __shared__ float Bs[32][68];   // [k][n], padded
    const int tid = threadIdx.x;
    const int bm = blockIdx.x * 64;
    const int bn = blockIdx.y * 64;
    const int tx = tid & 15, ty = tid >> 4;
    const int a_r = tid >> 3;          // 0..31
    const int a_c = (tid & 7) * 4;     // 0..28
    const int bc  = bn + tx * 4;

    float acc[4][4] = {};
    for (int k0 = 0; k0 < K; k0 += 32) {
        float4 av0 = *(const float4*)(A + (size_t)(bm + a_r) * K + (k0 + a_c));
        float4 av1 = *(const float4*)(A + (size_t)(bm + a_r + 32) * K + (k0 + a_c));
        float4 bv0 = make_float4(0.f, 0.f, 0.f, 0.f);
        float4 bv1 = make_float4(0.f, 0.f, 0.f, 0.f);
        if (bc + 3 < N) {
            bv0 = *(const float4*)(B + (size_t)(k0 + ty) * N + bc);
            bv1 = *(const float4*)(B + (size_t)(k0 + ty + 16) * N + bc);
        }
        __syncthreads();
        As[a_c + 0][a_r] = av0.x; As[a_c + 1][a_r] = av0.y;
        As[a_c + 2][a_r] = av0.z; As[a_c + 3][a_r] = av0.w;
        As[a_c + 0][a_r + 32] = av1.x; As[a_c + 1][a_r + 32] = av1.y;
        As[a_c + 2][a_r + 32] = av1.z; As[a_c + 3][a_r + 32] = av1.w;
        *(float4*)&Bs[ty][tx * 4]      = bv0;
        *(float4*)&Bs[ty + 16][tx * 4] = bv1;
        __syncthreads();
#pragma unroll
        for (int k = 0; k < 32; k++) {
            float4 a4 = *(const float4*)&As[k][ty * 4];
            float4 b4 = *(const float4*)&Bs[k][tx * 4];
            float a_[4] = {a4.x, a4.y, a4.z, a4.w};
            float b_[4] = {b4.x, b4.y, b4.z, b4.w};
#pragma unroll
            for (int i = 0; i < 4; i++)
#pragma unroll
                for (int j = 0; j < 4; j++) acc[i][j] += a_[i] * b_[j];
        }
    }
    if (bc + 3 < N) {
        float4 bsv = *(const float4*)(bias + bc);
#pragma unroll
        for (int i = 0; i < 4; i++) {
            const int r = bm + ty * 4 + i;
            float4 o;
            o.x = acc[i][0] + bsv.x; o.y = acc[i][1] + bsv.y;
            o.z = acc[i][2] + bsv.z; o.w = acc[i][3] + bsv.w;
            *(float4*)(C + (size_t)r * N + bc) = o;
        }
    }
}

// In-place LayerNorm(C=256) + leaky(0.01). One block per row.
__global__ __launch_bounds__(256) void ln_leaky_c256(
    float* __restrict__ f, const float* __restrict__ g, const float* __restrict__ b)
{
    const int row = blockIdx.x;
    const int t = threadIdx.x;
    float v = f[(size_t)row * 256 + t];
    float s = v, s2 = v * v;
#pragma unroll
    for (int off = 32; off >= 1; off >>= 1) {
        s += __shfl_xor(s, off);
        s2 += __shfl_xor(s2, off);
    }
    __shared__ float ws[4], ws2[4];
    const int wid = t >> 6, lane = t & 63;
    if (lane == 0) { ws[wid] = s; ws2[wid] = s2; }
    __syncthreads();
    const float S = ws[0] + ws[1] + ws[2] + ws[3];
    const float S2 = ws2[0] + ws2[1] + ws2[2] + ws2[3];
    const float mu = S * (1.0f / 256.0f);
    const float var = S2 * (1.0f / 256.0f) - mu * mu;
    float y = (v - mu) * rsqrtf(var + 1e-5f) * g[t] + b[t];
    f[(size_t)row * 256 + t] = (y >= 0.f) ? y : 0.01f * y;
}

// In-place LayerNorm(C=64) + leaky(0.01). One wave per row, 4 rows/block.
__global__ __launch_bounds__(256) void ln_leaky_c64(
    float* __restrict__ f, const float* __restrict__ g, const float* __restrict__ b)
{
    const int wid = threadIdx.x >> 6, lane = threadIdx.x & 63;
    const int row = blockIdx.x * 4 + wid;
    float v = f[(size_t)row * 64 + lane];
    float s = v, s2 = v * v;
#pragma unroll
    for (int off = 32; off >= 1; off >>= 1) {
        s += __shfl_xor(s, off);
        s2 += __shfl_xor(s2, off);
    }
    const float mu = s * (1.0f / 64.0f);
    const float var = s2 * (1.0f / 64.0f) - mu * mu;
    float y = (v - mu) * rsqrtf(var + 1e-5f) * g[lane] + b[lane];
    f[(size_t)row * 64 + lane] = (y >= 0.f) ? y : 0.01f * y;
}

// f3 = leaky(LN(f2 @ W3 + b3)).  8 threads per row (one per output col).
__global__ __launch_bounds__(256) void l3_ln_leaky(
    const float* __restrict__ f2, const float* __restrict__ W3,
    const float* __restrict__ b3,
    const float* __restrict__ g, const float* __restrict__ b,
    float* __restrict__ f3)
{
    __shared__ float sW[64 * 8];
    const int t = threadIdx.x;
    sW[t] = W3[t]; sW[t + 256] = W3[t + 256];
    __syncthreads();
    const int row = blockIdx.x * 32 + (t >> 3);
    const int c = t & 7;
    float acc = b3[c];
    const float* fr = f2 + (size_t)row * 64;
#pragma unroll 8
    for (int k = 0; k < 64; k++) acc += fr[k] * sW[k * 8 + c];
    float s = acc, s2 = acc * acc;
#pragma unroll
    for (int off = 4; off >= 1; off >>= 1) {
        s += __shfl_xor(s, off);
        s2 += __shfl_xor(s2, off);
    }
    const float mu = s * (1.0f / 8.0f);
    const float var = s2 * (1.0f / 8.0f) - mu * mu;
    float y = (acc - mu) * rsqrtf(var + 1e-5f) * g[c] + b[c];
    f3[(size_t)row * 8 + c] = (y >= 0.f) ? y : 0.01f * y;
}

// xf = leaky(LN(flat @ fl_W + fl_b)). One block per graph; 8 partials/col.
__global__ __launch_bounds__(256) void flat_ln_leaky(
    const float* __restrict__ f3, const float* __restrict__ W,
    const float* __restrict__ bb,
    const float* __restrict__ g, const float* __restrict__ b,
    float* __restrict__ xf)
{
    __shared__ float sf[1024];
    __shared__ float sp[8][32];
    const int t = threadIdx.x;
    const int gb = blockIdx.x;
    *(float4*)&sf[t * 4] = *(const float4*)(f3 + (size_t)gb * 1024 + t * 4);
    __syncthreads();
    const int c = t & 31, part = t >> 5;
    float acc = 0.f;
    for (int k = part * 128; k < part * 128 + 128; k++) acc += sf[k] * W[k * 32 + c];
    sp[part][c] = acc;
    __syncthreads();
    if (t < 32) {
        float v = bb[t];
#pragma unroll
        for (int p = 0; p < 8; p++) v += sp[p][t];
        float s = v, s2 = v * v;
#pragma unroll
        for (int off = 16; off >= 1; off >>= 1) {
            s += __shfl_xor(s, off);
            s2 += __shfl_xor(s2, off);
        }
        const float mu = s * (1.0f / 32.0f);
        const float var = s2 * (1.0f / 32.0f) - mu * mu;
        float y = (v - mu) * rsqrtf(var + 1e-5f) * g[t] + b[t];
        xf[gb * 32 + t] = (y >= 0.f) ? y : 0.01f * y;
    }
}

// out[b,o] = cat(gsum/cnt, xf, one_hot) @ out_W + out_b
__global__ __launch_bounds__(128) void final_out(
    const float* __restrict__ gsum, const float* __restrict__ gcnt,
    const float* __restrict__ xf, const float* __restrict__ onehot,
    const float* __restrict__ Wo, const float* __restrict__ bo,
    float* __restrict__ out)
{
    const int t = threadIdx.x;        // 128 = 64 graphs * 2 outputs
    const int gb = t >> 1, o = t & 1;
    float cnt = gcnt[gb];
    cnt = (cnt > 1.f) ? cnt : 1.f;
    float acc = bo[o];
#pragma unroll
    for (int j = 0; j < 4; j++)  acc += (gsum[gb * 4 + j] / cnt) * Wo[j * 2 + o];
#pragma unroll
    for (int j = 0; j < 32; j++) acc += xf[gb * 32 + j] * Wo[(4 + j) * 2 + o];
#pragma unroll
    for (int j = 0; j < 20; j++) acc += onehot[gb * 20 + j] * Wo[(36 + j) * 2 + o];
    out[t] = acc;
}

extern "C" void kernel_launch(void* const* d_in, const int* in_sizes, int n_in,
                              void* d_out, int out_size, void* d_ws, size_t ws_size,
                              hipStream_t stream)
{
    const float* x        = (const float*)d_in[0];
    const int*   ei       = (const int*)d_in[1];
    const int*   batch    = (const int*)d_in[2];
    const float* features = (const float*)d_in[3];
    const float* one_hot  = (const float*)d_in[4];
    const float* W_l   = (const float*)d_in[5];
    const float* b_l   = (const float*)d_in[6];
    const float* W_r   = (const float*)d_in[7];
    const float* b_r   = (const float*)d_in[8];
    const float* att   = (const float*)d_in[9];
    const float* conv_b = (const float*)d_in[10];
    const float* jk_W  = (const float*)d_in[11];
    const float* jk_b  = (const float*)d_in[12];
    const float* l1_W  = (const float*)d_in[13];
    const float* l1_b  = (const float*)d_in[14];
    const float* ln1_g = (const float*)d_in[15];
    const float* ln1_b = (const float*)d_in[16];
    const float* l2_W  = (const float*)d_in[17];
    const float* l2_b  = (const float*)d_in[18];
    const float* ln2_g = (const float*)d_in[19];
    const float* ln2_b = (const float*)d_in[20];
    const float* l3_W  = (const float*)d_in[21];
    const float* l3_b  = (const float*)d_in[22];
    const float* ln3_g = (const float*)d_in[23];
    const float* ln3_b = (const float*)d_in[24];
    const float* fl_W  = (const float*)d_in[25];
    const float* fl_b  = (const float*)d_in[26];
    const float* ln4_g = (const float*)d_in[27];
    const float* ln4_b = (const float*)d_in[28];
    const float* out_W = (const float*)d_in[29];
    const float* out_b = (const float*)d_in[30];
    (void)in_sizes; (void)n_in; (void)out_size; (void)ws_size;

    float* ws   = (float*)d_ws;
    float* z    = ws + 0;
    float* agg  = ws + 200000;
    float* gsum = ws + 1400000;
    float* gcnt = ws + 1400256;
    float* xl   = ws + 1400320;
    float* xr   = ws + 3000320;
    float* f1   = ws + 4600320;
    float* f2   = ws + 6697472;
    float* f3   = ws + 7221760;
    float* xf   = ws + 7287296;

    // zero the accumulators (z, agg, gsum, gcnt are contiguous)
    hipMemsetAsync(z, 0, (size_t)1400320 * sizeof(float), stream);

    node_xform<<<N_NODES / 16, 256, 0, stream>>>(x, W_l, b_l, W_r, b_r, xl, xr);
    edge_attn<<<(N_EDGES + N_NODES + 255) / 256, 256, 0, stream>>>(ei, xl, xr, att, z, agg);
    finalize_pool<<<(N_NODES + 255) / 256, 256, 0, stream>>>(agg, z, conv_b, jk_W, jk_b,
                                                             batch, gsum, gcnt);
    gemm64<<<dim3(MROWS / 64, 256 / 64), 256, 0, stream>>>(features, l1_W, l1_b, f1,
                                                           MROWS, 256, FEAT);
    ln_leaky_c256<<<MROWS, 256, 0, stream>>>(f1, ln1_g, ln1_b);
    gemm64<<<dim3(MROWS / 64, 1), 256, 0, stream>>>(f1, l2_W, l2_b, f2, MROWS, 64, 256);
    ln_leaky_c64<<<MROWS / 4, 256, 0, stream>>>(f2, ln2_g, ln2_b);
    l3_ln_leaky<<<MROWS / 32, 256, 0, stream>>>(f2, l3_W, l3_b, ln3_g, ln3_b, f3);
    flat_ln_leaky<<<NB, 256, 0, stream>>>(f3, fl_W, fl_b, ln4_g, ln4_b, xf);
    final_out<<<1, 128, 0, stream>>>(gsum, gcnt, xf, one_hot, out_W, out_b, (float*)d_out);
}

// Round 2
// 1058.905 us; speedup vs baseline: 2.6444x; 2.6444x over previous
//
#include <hip/hip_runtime.h>
#include <cstdint>
#include <cstddef>

#define N_NODES 200000
#define N_EDGES 6400000
#define NB      64
#define MROWS   8192     // NB*ROWS
#define FEAT    2560

// edge bucketing: bucket = 256 consecutive dst nodes
#define NBK   782        // ceil(200000/256)
#define HBLK  128        // histogram/scatter blocks
#define ETILE 50000      // edges per block (HBLK*ETILE == N_EDGES exactly)

// ---------------------------------------------------------------------------
// Workspace layout (4-byte units):
//   xl        [200000*8]   @ 0          (padded stride 8 for aligned gathers)
//   xr        [200000*8]   @ 1600000
//   f1        [8192*256]   @ 3200000
//   f2        [8192*64]    @ 5297152
//   f3        [8192*8]     @ 5821440
//   xf        [64*32]      @ 5886976
//   gsum      [256]        @ 5889024   -- memset span (320 floats)
//   gcnt      [64]         @ 5889280   --
//   bstart    [784]        @ 5889344
//   bhist     [128*782]    @ 5890128
//   bofs      [128*782]    @ 5990224
//   pairs     [6400000]    @ 6090320   (int: src<<8 | dst&255)
// end = 12,490,320 floats = 50.0 MB
// ---------------------------------------------------------------------------

// xl = x@W_l + b_l, xr = x@W_r + b_r.  16 lanes per node; W rows in registers.
__global__ __launch_bounds__(256) void node_xform(
    const float* __restrict__ x,
    const float* __restrict__ Wl, const float* __restrict__ bl,
    const float* __restrict__ Wr, const float* __restrict__ br,
    float* __restrict__ xl, float* __restrict__ xr)
{
    const int t = threadIdx.x;
    const int l = t & 15;
    const int node = blockIdx.x * 16 + (t >> 4);

    float wl[48], wr[48];
#pragma unroll
    for (int q = 0; q < 12; q++) {
        *(float4*)&wl[q * 4] = *(const float4*)(Wl + 48 * l + 4 * q);
        *(float4*)&wr[q * 4] = *(const float4*)(Wr + 48 * l + 4 * q);
    }
    float xv[8];
    *(float4*)&xv[0] = *(const float4*)(x + (size_t)node * 128 + l * 8);
    *(float4*)&xv[4] = *(const float4*)(x + (size_t)node * 128 + l * 8 + 4);

    float al[6] = {}, ar[6] = {};
#pragma unroll
    for (int i = 0; i < 8; i++) {
#pragma unroll
        for (int j = 0; j < 6; j++) {
            al[j] += xv[i] * wl[i * 6 + j];
            ar[j] += xv[i] * wr[i * 6 + j];
        }
    }
#pragma unroll
    for (int off = 8; off >= 1; off >>= 1) {
#pragma unroll
        for (int j = 0; j < 6; j++) {
            al[j] += __shfl_xor(al[j], off);
            ar[j] += __shfl_xor(ar[j], off);
        }
    }
    if (l == 0) {
#pragma unroll
        for (int j = 0; j < 6; j++) {
            xl[(size_t)node * 8 + j] = al[j] + bl[j];
            xr[(size_t)node * 8 + j] = ar[j] + br[j];
        }
    }
}

// Pass 1: per-block LDS histogram of dst buckets. No global atomics.
__global__ __launch_bounds__(256) void edge_hist(
    const int* __restrict__ ei, int* __restrict__ bhist)
{
    __shared__ int h[NBK];
    for (int i = threadIdx.x; i < NBK; i += 256) h[i] = 0;
    __syncthreads();
    const int base = blockIdx.x * ETILE;
    const int end = base + ETILE;
    for (int i = base + threadIdx.x; i < end; i += 256) {
        const int d = ei[N_EDGES + i];
        atomicAdd(&h[d >> 8], 1);
    }
    __syncthreads();
    for (int i = threadIdx.x; i < NBK; i += 256)
        bhist[blockIdx.x * NBK + i] = h[i];
}

// Pass 2: bucket bases + per-(block,bucket) scatter offsets. One block.
__global__ __launch_bounds__(1024) void edge_scan(
    const int* __restrict__ bhist, int* __restrict__ bofs, int* __restrict__ bstart)
{
    __shared__ int colsum[NBK];
    __shared__ int basev[NBK];
    const int t = threadIdx.x;
    if (t < NBK) {
        int s = 0;
        for (int blk = 0; blk < HBLK; blk++) s += bhist[blk * NBK + t];
        colsum[t] = s;
    }
    __syncthreads();
    if (t == 0) {
        int run = 0;
        for (int b = 0; b < NBK; b++) { basev[b] = run; run += colsum[b]; }
    }
    __syncthreads();
    if (t < NBK) {
        int run = basev[t];
        bstart[t] = run;
        for (int blk = 0; blk < HBLK; blk++) {
            bofs[blk * NBK + t] = run;
            run += bhist[blk * NBK + t];
        }
        if (t == 0) bstart[NBK] = N_EDGES;
    }
}

// Pass 3: scatter edges into bucket-contiguous order. pairs = src<<8 | dst&255.
__global__ __launch_bounds__(256) void edge_scatter(
    const int* __restrict__ ei, const int* __restrict__ bofs, int* __restrict__ pairs)
{
    __shared__ int cnt[NBK];
    for (int i = threadIdx.x; i < NBK; i += 256)
        cnt[i] = bofs[blockIdx.x * NBK + i];
    __syncthreads();
    const int base = blockIdx.x * ETILE;
    const int end = base + ETILE;
    for (int i = base + threadIdx.x; i < end; i += 256) {
        const int d = ei[N_EDGES + i];
        const int s = ei[i];
        const int pos = atomicAdd(&cnt[d >> 8], 1);
        pairs[pos] = (s << 8) | (d & 255);
    }
}

// Pass 4: one block per bucket. z/agg accumulate in LDS (float atomics);
// self-loop added implicitly at finalize; fused leaky+jk+segment-mean pooling.
__global__ __launch_bounds__(256) void bucket_reduce(
    const int* __restrict__ pairs, const int* __restrict__ bstart,
    const float* __restrict__ xl, const float* __restrict__ xr,
    const float* __restrict__ att, const float* __restrict__ conv_b,
    const float* __restrict__ jkW, const float* __restrict__ jkb,
    const int* __restrict__ batch,
    float* __restrict__ gsum, float* __restrict__ gcnt)
{
    __shared__ float acc[256][7];   // [ls][0..5]=agg, [ls][6]=z
    __shared__ float xrs[256][6];
    const int t = threadIdx.x;
    const int d0 = blockIdx.x * 256 + t;

    if (d0 < N_NODES) {
        float4 a = *(const float4*)(xr + (size_t)d0 * 8);
        float2 b = *(const float2*)(xr + (size_t)d0 * 8 + 4);
        xrs[t][0] = a.x; xrs[t][1] = a.y; xrs[t][2] = a.z;
        xrs[t][3] = a.w; xrs[t][4] = b.x; xrs[t][5] = b.y;
    }
#pragma unroll
    for (int j = 0; j < 7; j++) acc[t][j] = 0.f;
    __syncthreads();

    float attv[6];
#pragma unroll
    for (int j = 0; j < 6; j++) attv[j] = att[j];

    const int e0 = bstart[blockIdx.x], e1 = bstart[blockIdx.x + 1];
    for (int i = e0 + t; i < e1; i += 256) {
        const int v = pairs[i];
        const int ls = v & 255;
        const int s = ((unsigned)v) >> 8;
        float4 a = *(const float4*)(xl + (size_t)s * 8);
        float2 b2 = *(const float2*)(xl + (size_t)s * 8 + 4);
        float xls[6] = {a.x, a.y, a.z, a.w, b2.x, b2.y};
        float sc = 0.f;
#pragma unroll
        for (int j = 0; j < 6; j++) {
            float e = xls[j] + xrs[ls][j];
            e = (e >= 0.f) ? e : 0.2f * e;
            sc += attv[j] * e;
        }
        const float p = __expf(sc);
        atomicAdd(&acc[ls][6], p);
#pragma unroll
        for (int j = 0; j < 6; j++)
            atomicAdd(&acc[ls][j], p * xls[j]);
    }
    __syncthreads();

    // finalize node d0: self-loop + normalize + leaky + jk
    float h[4] = {0.f, 0.f, 0.f, 0.f};
    float cw = 0.f;
    int b = 0;
    if (d0 < N_NODES) {
        float4 a = *(const float4*)(xl + (size_t)d0 * 8);
        float2 b2 = *(const float2*)(xl + (size_t)d0 * 8 + 4);
        float xld[6] = {a.x, a.y, a.z, a.w, b2.x, b2.y};
        float sc = 0.f;
#pragma unroll
        for (int j = 0; j < 6; j++) {
            float e = xld[j] + xrs[t][j];
            e = (e >= 0.f) ? e : 0.2f * e;
            sc += attv[j] * e;
        }
        const float p = __expf(sc);
        const float z = acc[t][6] + p;
#pragma unroll
        for (int c = 0; c < 4; c++) h[c] = jkb[c];
#pragma unroll
        for (int j = 0; j < 6; j++) {
            float aj = (acc[t][j] + p * xld[j]) / z + conv_b[j];
            aj = (aj >= 0.f) ? aj : 0.01f * aj;
#pragma unroll
            for (int c = 0; c < 4; c++) h[c] += aj * jkW[j * 4 + c];
        }
        b = batch[d0];
        cw = 1.f;
    }
    const int b0 = __shfl(b, 0);
    if (__all(b == b0)) {
#pragma unroll
        for (int off = 32; off >= 1; off >>= 1) {
#pragma unroll
            for (int c = 0; c < 4; c++) h[c] += __shfl_xor(h[c], off);
            cw += __shfl_xor(cw, off);
        }
        if ((t & 63) == 0 && cw > 0.f) {
#pragma unroll
            for (int c = 0; c < 4; c++) atomicAdd(gsum + b0 * 4 + c, h[c]);
            atomicAdd(gcnt + b0, cw);
        }
    } else if (cw > 0.f) {
#pragma unroll
        for (int c = 0; c < 4; c++) atomicAdd(gsum + b * 4 + c, h[c]);
        atomicAdd(gcnt + b, cw);
    }
}

// C[M,N] = A[M,K] @ B[K,N] + bias.  64x64 tile, BK=32, 256 threads, 4x4/thread.
__global__ __launch_bounds__(256) void gemm64(
    const float* __restrict__ A, const float* __restrict__ B,
    const float* __restrict__ bias, float* __restrict__ C,
    int M, int N, int K)
{
    __shared__ float As[32][68];   // [k][m], padded
    __shared__ float Bs[32][68];   // [k][n], padded
    const int tid = threadIdx.x;
    const int bm = blockIdx.x * 64;
    const int bn = blockIdx.y * 64;
    const int tx = tid & 15, ty = tid >> 4;
    const int a_r = tid >> 3;          // 0..31
    const int a_c = (tid & 7) * 4;     // 0..28
    const int bc  = bn + tx * 4;

    float acc[4][4] = {};
    for (int k0 = 0; k0 < K; k0 += 32) {
        float4 av0 = *(const float4*)(A + (size_t)(bm + a_r) * K + (k0 + a_c));
        float4 av1 = *(const float4*)(A + (size_t)(bm + a_r + 32) * K + (k0 + a_c));
        float4 bv0 = make_float4(0.f, 0.f, 0.f, 0.f);
        float4 bv1 = make_float4(0.f, 0.f, 0.f, 0.f);
        if (bc + 3 < N) {
            bv0 = *(const float4*)(B + (size_t)(k0 + ty) * N + bc);
            bv1 = *(const float4*)(B + (size_t)(k0 + ty + 16) * N + bc);
        }
        __syncthreads();
        As[a_c + 0][a_r] = av0.x; As[a_c + 1][a_r] = av0.y;
        As[a_c + 2][a_r] = av0.z; As[a_c + 3][a_r] = av0.w;
        As[a_c + 0][a_r + 32] = av1.x; As[a_c + 1][a_r + 32] = av1.y;
        As[a_c + 2][a_r + 32] = av1.z; As[a_c + 3][a_r + 32] = av1.w;
        *(float4*)&Bs[ty][tx * 4]      = bv0;
        *(float4*)&Bs[ty + 16][tx * 4] = bv1;
        __syncthreads();
#pragma unroll
        for (int k = 0; k < 32; k++) {
            float4 a4 = *(const float4*)&As[k][ty * 4];
            float4 b4 = *(const float4*)&Bs[k][tx * 4];
            float a_[4] = {a4.x, a4.y, a4.z, a4.w};
            float b_[4] = {b4.x, b4.y, b4.z, b4.w};
#pragma unroll
            for (int i = 0; i < 4; i++)
#pragma unroll
                for (int j = 0; j < 4; j++) acc[i][j] += a_[i] * b_[j];
        }
    }
    if (bc + 3 < N) {
        float4 bsv = *(const float4*)(bias + bc);
#pragma unroll
        for (int i = 0; i < 4; i++) {
            const int r = bm + ty * 4 + i;
            float4 o;
            o.x = acc[i][0] + bsv.x; o.y = acc[i][1] + bsv.y;
            o.z = acc[i][2] + bsv.z; o.w = acc[i][3] + bsv.w;
            *(float4*)(C + (size_t)r * N + bc) = o;
        }
    }
}

// In-place LayerNorm(C=256) + leaky(0.01). One block per row.
__global__ __launch_bounds__(256) void ln_leaky_c256(
    float* __restrict__ f, const float* __restrict__ g, const float* __restrict__ b)
{
    const int row = blockIdx.x;
    const int t = threadIdx.x;
    float v = f[(size_t)row * 256 + t];
    float s = v, s2 = v * v;
#pragma unroll
    for (int off = 32; off >= 1; off >>= 1) {
        s += __shfl_xor(s, off);
        s2 += __shfl_xor(s2, off);
    }
    __shared__ float ws[4], ws2[4];
    const int wid = t >> 6, lane = t & 63;
    if (lane == 0) { ws[wid] = s; ws2[wid] = s2; }
    __syncthreads();
    const float S = ws[0] + ws[1] + ws[2] + ws[3];
    const float S2 = ws2[0] + ws2[1] + ws2[2] + ws2[3];
    const float mu = S * (1.0f / 256.0f);
    const float var = S2 * (1.0f / 256.0f) - mu * mu;
    float y = (v - mu) * rsqrtf(var + 1e-5f) * g[t] + b[t];
    f[(size_t)row * 256 + t] = (y >= 0.f) ? y : 0.01f * y;
}

// In-place LayerNorm(C=64) + leaky(0.01). One wave per row, 4 rows/block.
__global__ __launch_bounds__(256) void ln_leaky_c64(
    float* __restrict__ f, const float* __restrict__ g, const float* __restrict__ b)
{
    const int wid = threadIdx.x >> 6, lane = threadIdx.x & 63;
    const int row = blockIdx.x * 4 + wid;
    float v = f[(size_t)row * 64 + lane];
    float s = v, s2 = v * v;
#pragma unroll
    for (int off = 32; off >= 1; off >>= 1) {
        s += __shfl_xor(s, off);
        s2 += __shfl_xor(s2, off);
    }
    const float mu = s * (1.0f / 64.0f);
    const float var = s2 * (1.0f / 64.0f) - mu * mu;
    float y = (v - mu) * rsqrtf(var + 1e-5f) * g[lane] + b[lane];
    f[(size_t)row * 64 + lane] = (y >= 0.f) ? y : 0.01f * y;
}

// f3 = leaky(LN(f2 @ W3 + b3)).  8 threads per row (one per output col).
__global__ __launch_bounds__(256) void l3_ln_leaky(
    const float* __restrict__ f2, const float* __restrict__ W3,
    const float* __restrict__ b3,
    const float* __restrict__ g, const float* __restrict__ b,
    float* __restrict__ f3)
{
    __shared__ float sW[64 * 8];
    const int t = threadIdx.x;
    sW[t] = W3[t]; sW[t + 256] = W3[t + 256];
    __syncthreads();
    const int row = blockIdx.x * 32 + (t >> 3);
    const int c = t & 7;
    float acc = b3[c];
    const float* fr = f2 + (size_t)row * 64;
#pragma unroll 8
    for (int k = 0; k < 64; k++) acc += fr[k] * sW[k * 8 + c];
    float s = acc, s2 = acc * acc;
#pragma unroll
    for (int off = 4; off >= 1; off >>= 1) {
        s += __shfl_xor(s, off);
        s2 += __shfl_xor(s2, off);
    }
    const float mu = s * (1.0f / 8.0f);
    const float var = s2 * (1.0f / 8.0f) - mu * mu;
    float y = (acc - mu) * rsqrtf(var + 1e-5f) * g[c] + b[c];
    f3[(size_t)row * 8 + c] = (y >= 0.f) ? y : 0.01f * y;
}

// xf = leaky(LN(flat @ fl_W + fl_b)). One block per graph; 8 partials/col.
__global__ __launch_bounds__(256) void flat_ln_leaky(
    const float* __restrict__ f3, const float* __restrict__ W,
    const float* __restrict__ bb,
    const float* __restrict__ g, const float* __restrict__ b,
    float* __restrict__ xf)
{
    __shared__ float sf[1024];
    __shared__ float sp[8][32];
    const int t = threadIdx.x;
    const int gb = blockIdx.x;
    *(float4*)&sf[t * 4] = *(const float4*)(f3 + (size_t)gb * 1024 + t * 4);
    __syncthreads();
    const int c = t & 31, part = t >> 5;
    float acc = 0.f;
    for (int k = part * 128; k < part * 128 + 128; k++) acc += sf[k] * W[k * 32 + c];
    sp[part][c] = acc;
    __syncthreads();
    if (t < 32) {
        float v = bb[t];
#pragma unroll
        for (int p = 0; p < 8; p++) v += sp[p][t];
        float s = v, s2 = v * v;
#pragma unroll
        for (int off = 16; off >= 1; off >>= 1) {
            s += __shfl_xor(s, off);
            s2 += __shfl_xor(s2, off);
        }
        const float mu = s * (1.0f / 32.0f);
        const float var = s2 * (1.0f / 32.0f) - mu * mu;
        float y = (v - mu) * rsqrtf(var + 1e-5f) * g[t] + b[t];
        xf[gb * 32 + t] = (y >= 0.f) ? y : 0.01f * y;
    }
}

// out[b,o] = cat(gsum/cnt, xf, one_hot) @ out_W + out_b
__global__ __launch_bounds__(128) void final_out(
    const float* __restrict__ gsum, const float* __restrict__ gcnt,
    const float* __restrict__ xf, const float* __restrict__ onehot,
    const float* __restrict__ Wo, const float* __restrict__ bo,
    float* __restrict__ out)
{
    const int t = threadIdx.x;        // 128 = 64 graphs * 2 outputs
    const int gb = t >> 1, o = t & 1;
    float cnt = gcnt[gb];
    cnt = (cnt > 1.f) ? cnt : 1.f;
    float acc = bo[o];
#pragma unroll
    for (int j = 0; j < 4; j++)  acc += (gsum[gb * 4 + j] / cnt) * Wo[j * 2 + o];
#pragma unroll
    for (int j = 0; j < 32; j++) acc += xf[gb * 32 + j] * Wo[(4 + j) * 2 + o];
#pragma unroll
    for (int j = 0; j < 20; j++) acc += onehot[gb * 20 + j] * Wo[(36 + j) * 2 + o];
    out[t] = acc;
}

extern "C" void kernel_launch(void* const* d_in, const int* in_sizes, int n_in,
                              void* d_out, int out_size, void* d_ws, size_t ws_size,
                              hipStream_t stream)
{
    const float* x        = (const float*)d_in[0];
    const int*   ei       = (const int*)d_in[1];
    const int*   batch    = (const int*)d_in[2];
    const float* features = (const float*)d_in[3];
    const float* one_hot  = (const float*)d_in[4];
    const float* W_l   = (const float*)d_in[5];
    const float* b_l   = (const float*)d_in[6];
    const float* W_r   = (const float*)d_in[7];
    const float* b_r   = (const float*)d_in[8];
    const float* att   = (const float*)d_in[9];
    const float* conv_b = (const float*)d_in[10];
    const float* jk_W  = (const float*)d_in[11];
    const float* jk_b  = (const float*)d_in[12];
    const float* l1_W  = (const float*)d_in[13];
    const float* l1_b  = (const float*)d_in[14];
    const float* ln1_g = (const float*)d_in[15];
    const float* ln1_b = (const float*)d_in[16];
    const float* l2_W  = (const float*)d_in[17];
    const float* l2_b  = (const float*)d_in[18];
    const float* ln2_g = (const float*)d_in[19];
    const float* ln2_b = (const float*)d_in[20];
    const float* l3_W  = (const float*)d_in[21];
    const float* l3_b  = (const float*)d_in[22];
    const float* ln3_g = (const float*)d_in[23];
    const float* ln3_b = (const float*)d_in[24];
    const float* fl_W  = (const float*)d_in[25];
    const float* fl_b  = (const float*)d_in[26];
    const float* ln4_g = (const float*)d_in[27];
    const float* ln4_b = (const float*)d_in[28];
    const float* out_W = (const float*)d_in[29];
    const float* out_b = (const float*)d_in[30];
    (void)in_sizes; (void)n_in; (void)out_size; (void)ws_size;

    float* ws     = (float*)d_ws;
    float* xl     = ws + 0;
    float* xr     = ws + 1600000;
    float* f1     = ws + 3200000;
    float* f2     = ws + 5297152;
    float* f3     = ws + 5821440;
    float* xf     = ws + 5886976;
    float* gsum   = ws + 5889024;
    float* gcnt   = ws + 5889280;
    int*   bstart = (int*)(ws + 5889344);
    int*   bhist  = (int*)(ws + 5890128);
    int*   bofs   = (int*)(ws + 5990224);
    int*   pairs  = (int*)(ws + 6090320);

    // zero pooled accumulators only (gsum+gcnt contiguous, 320 floats)
    hipMemsetAsync(gsum, 0, 320 * sizeof(float), stream);

    node_xform<<<N_NODES / 16, 256, 0, stream>>>(x, W_l, b_l, W_r, b_r, xl, xr);
    edge_hist<<<HBLK, 256, 0, stream>>>(ei, bhist);
    edge_scan<<<1, 1024, 0, stream>>>(bhist, bofs, bstart);
    edge_scatter<<<HBLK, 256, 0, stream>>>(ei, bofs, pairs);
    bucket_reduce<<<NBK, 256, 0, stream>>>(pairs, bstart, xl, xr, att, conv_b,
                                           jk_W, jk_b, batch, gsum, gcnt);
    gemm64<<<dim3(MROWS / 64, 256 / 64), 256, 0, stream>>>(features, l1_W, l1_b, f1,
                                                           MROWS, 256, FEAT);
    ln_leaky_c256<<<MROWS, 256, 0, stream>>>(f1, ln1_g, ln1_b);
    gemm64<<<dim3(MROWS / 64, 1), 256, 0, stream>>>(f1, l2_W, l2_b, f2, MROWS, 64, 256);
    ln_leaky_c64<<<MROWS / 4, 256, 0, stream>>>(f2, ln2_g, ln2_b);
    l3_ln_leaky<<<MROWS / 32, 256, 0, stream>>>(f2, l3_W, l3_b, ln3_g, ln3_b, f3);
    flat_ln_leaky<<<NB, 256, 0, stream>>>(f3, fl_W, fl_b, ln4_g, ln4_b, xf);
    final_out<<<1, 128, 0, stream>>>(gsum, gcnt, xf, one_hot, out_W, out_b, (float*)d_out);
}

// Round 3
// 969.226 us; speedup vs baseline: 2.8891x; 1.0925x over previous
//
#include <hip/hip_runtime.h>
#include <cstdint>
#include <cstddef>

#define N_NODES 200000
#define N_EDGES 6400000
#define NB      64
#define MROWS   8192     // NB*ROWS
#define FEAT    2560

// edge bucketing: bucket = 128 consecutive dst nodes
#define BSZ   128
#define NBK   1563       // ceil(200000/128)
#define HBLK  128        // histogram/scatter blocks
#define ETILE 50000      // edges per block (HBLK*ETILE == N_EDGES)

typedef __attribute__((ext_vector_type(8))) short bf16x8;
typedef __attribute__((ext_vector_type(4))) float f32x4;

__device__ __forceinline__ unsigned short bf16rne(float f) {
    unsigned u = __builtin_bit_cast(unsigned, f);
    u += 0x7fffu + ((u >> 16) & 1u);
    return (unsigned short)(u >> 16);
}

__device__ __forceinline__ void async_cp16(const void* g, void* l) {
    __builtin_amdgcn_global_load_lds(
        (const __attribute__((address_space(1))) unsigned int*)g,
        (__attribute__((address_space(3))) unsigned int*)l, 16, 0, 0);
}

// ---------------------------------------------------------------------------
// Workspace layout (4-byte units), edge scratch aliased over MLP scratch
// (bucket_reduce finishes before gemm L1 starts):
//   xlb  (bf16[200000][8])   @ 0         .. 800,000
//   xr   (f32 [200000][8])   @ 800,000   .. 2,400,000
//   w1t  (bf16[256][2560])   @ 2,400,000 .. 2,727,680
//   w2t  (bf16[64][256])     @ 2,727,680 .. 2,735,872
//   gsum [256]               @ 2,735,872 ; gcnt [64] @ 2,736,128  (memset 320)
//   union @ 2,736,192:
//     edge:  bstart[1564] @2,736,192; bhist @2,737,756; bofs @2,937,820;
//            pairs[6.4M] @3,137,884 .. 9,537,884
//     mlp:   f1 f32[8192*256] @2,736,192; f1b bf16 @4,833,344;
//            f2 @5,881,920; f3 @6,406,208; xf @6,471,744
// total 9,537,884 dw = 38.2 MB
// ---------------------------------------------------------------------------

// xl (bf16 packed, 16B/node) and xr (f32, stride 8) node transforms.
__global__ __launch_bounds__(256) void node_xform(
    const float* __restrict__ x,
    const float* __restrict__ Wl, const float* __restrict__ bl,
    const float* __restrict__ Wr, const float* __restrict__ br,
    unsigned short* __restrict__ xlb, float* __restrict__ xr)
{
    const int t = threadIdx.x;
    const int l = t & 15;
    const int node = blockIdx.x * 16 + (t >> 4);

    float wl[48], wr[48];
#pragma unroll
    for (int q = 0; q < 12; q++) {
        *(float4*)&wl[q * 4] = *(const float4*)(Wl + 48 * l + 4 * q);
        *(float4*)&wr[q * 4] = *(const float4*)(Wr + 48 * l + 4 * q);
    }
    float xv[8];
    *(float4*)&xv[0] = *(const float4*)(x + (size_t)node * 128 + l * 8);
    *(float4*)&xv[4] = *(const float4*)(x + (size_t)node * 128 + l * 8 + 4);

    float al[6] = {}, ar[6] = {};
#pragma unroll
    for (int i = 0; i < 8; i++) {
#pragma unroll
        for (int j = 0; j < 6; j++) {
            al[j] += xv[i] * wl[i * 6 + j];
            ar[j] += xv[i] * wr[i * 6 + j];
        }
    }
#pragma unroll
    for (int off = 8; off >= 1; off >>= 1) {
#pragma unroll
        for (int j = 0; j < 6; j++) {
            al[j] += __shfl_xor(al[j], off);
            ar[j] += __shfl_xor(ar[j], off);
        }
    }
    if (l == 0) {
        union { unsigned short h[8]; uint4 v; } u;
#pragma unroll
        for (int j = 0; j < 6; j++) u.h[j] = bf16rne(al[j] + bl[j]);
        u.h[6] = 0; u.h[7] = 0;
        *(uint4*)(xlb + (size_t)node * 8) = u.v;
        float4 r0; float2 r1;
        r0.x = ar[0] + br[0]; r0.y = ar[1] + br[1];
        r0.z = ar[2] + br[2]; r0.w = ar[3] + br[3];
        r1.x = ar[4] + br[4]; r1.y = ar[5] + br[5];
        *(float4*)(xr + (size_t)node * 8) = r0;
        *(float2*)(xr + (size_t)node * 8 + 4) = r1;
    }
}

// Pass 1: per-block LDS histogram of dst buckets.
__global__ __launch_bounds__(256) void edge_hist(
    const int* __restrict__ ei, int* __restrict__ bhist)
{
    __shared__ int h[NBK];
    for (int i = threadIdx.x; i < NBK; i += 256) h[i] = 0;
    __syncthreads();
    const int base = blockIdx.x * ETILE;
    const int end = base + ETILE;
    for (int i = base + threadIdx.x; i < end; i += 256)
        atomicAdd(&h[ei[N_EDGES + i] >> 7], 1);
    __syncthreads();
    for (int i = threadIdx.x; i < NBK; i += 256)
        bhist[blockIdx.x * NBK + i] = h[i];
}

// Pass 2: bucket bases + per-(block,bucket) scatter offsets. One block.
__global__ __launch_bounds__(1024) void edge_scan(
    const int* __restrict__ bhist, int* __restrict__ bofs, int* __restrict__ bstart)
{
    __shared__ int colsum[NBK];
    __shared__ int basev[NBK];
    const int t = threadIdx.x;
    for (int b = t; b < NBK; b += 1024) {
        int s = 0;
        for (int blk = 0; blk < HBLK; blk++) s += bhist[blk * NBK + b];
        colsum[b] = s;
    }
    __syncthreads();
    if (t == 0) {
        int run = 0;
        for (int b = 0; b < NBK; b++) { basev[b] = run; run += colsum[b]; }
        bstart[NBK] = N_EDGES;
    }
    __syncthreads();
    for (int b = t; b < NBK; b += 1024) {
        int run = basev[b];
        bstart[b] = run;
        for (int blk = 0; blk < HBLK; blk++) {
            bofs[blk * NBK + b] = run;
            run += bhist[blk * NBK + b];
        }
    }
}

// Pass 3: scatter edges into bucket-contiguous order. pairs = src<<7 | dst&127.
__global__ __launch_bounds__(256) void edge_scatter(
    const int* __restrict__ ei, const int* __restrict__ bofs, int* __restrict__ pairs)
{
    __shared__ int cnt[NBK];
    for (int i = threadIdx.x; i < NBK; i += 256)
        cnt[i] = bofs[blockIdx.x * NBK + i];
    __syncthreads();
    const int base = blockIdx.x * ETILE;
    const int end = base + ETILE;
    for (int i = base + threadIdx.x; i < end; i += 256) {
        const int d = ei[N_EDGES + i];
        const int s = ei[i];
        const int pos = atomicAdd(&cnt[d >> 7], 1);
        pairs[pos] = (s << 7) | (d & 127);
    }
}

// Pass 4: one block per 128-node bucket; LDS accumulate; fused finalize+pool.
__global__ __launch_bounds__(256) void bucket_reduce(
    const int* __restrict__ pairs, const int* __restrict__ bstart,
    const unsigned short* __restrict__ xlb, const float* __restrict__ xr,
    const float* __restrict__ att, const float* __restrict__ conv_b,
    const float* __restrict__ jkW, const float* __restrict__ jkb,
    const int* __restrict__ batch,
    float* __restrict__ gsum, float* __restrict__ gcnt)
{
    __shared__ float acc[BSZ][7];   // [ls][0..5]=agg, [ls][6]=z
    __shared__ float xrs[BSZ][6];
    const int t = threadIdx.x;
    const int d0 = blockIdx.x * BSZ + t;

    if (t < BSZ) {
        if (d0 < N_NODES) {
            float4 a = *(const float4*)(xr + (size_t)d0 * 8);
            float2 b = *(const float2*)(xr + (size_t)d0 * 8 + 4);
            xrs[t][0] = a.x; xrs[t][1] = a.y; xrs[t][2] = a.z;
            xrs[t][3] = a.w; xrs[t][4] = b.x; xrs[t][5] = b.y;
        } else {
#pragma unroll
            for (int j = 0; j < 6; j++) xrs[t][j] = 0.f;
        }
    }
    for (int i = t; i < BSZ * 7; i += 256) ((float*)acc)[i] = 0.f;
    __syncthreads();

    float attv[6];
#pragma unroll
    for (int j = 0; j < 6; j++) attv[j] = att[j];

    const uint4* xl4 = (const uint4*)xlb;
    const int e0 = bstart[blockIdx.x], e1 = bstart[blockIdx.x + 1];
    int i = e0 + t;
    for (; i + 256 < e1; i += 512) {
        const int v0 = pairs[i];
        const int v1 = pairs[i + 256];
        const uint4 g0 = xl4[((unsigned)v0) >> 7];
        const uint4 g1 = xl4[((unsigned)v1) >> 7];
        const uint4 gg[2] = {g0, g1};
        const int vv[2] = {v0, v1};
#pragma unroll
        for (int u = 0; u < 2; u++) {
            const int ls = vv[u] & 127;
            const uint4 g = gg[u];
            float xls[6];
            xls[0] = __builtin_bit_cast(float, g.x << 16);
            xls[1] = __builtin_bit_cast(float, g.x & 0xffff0000u);
            xls[2] = __builtin_bit_cast(float, g.y << 16);
            xls[3] = __builtin_bit_cast(float, g.y & 0xffff0000u);
            xls[4] = __builtin_bit_cast(float, g.z << 16);
            xls[5] = __builtin_bit_cast(float, g.z & 0xffff0000u);
            float sc = 0.f;
#pragma unroll
            for (int j = 0; j < 6; j++) {
                float e = xls[j] + xrs[ls][j];
                e = (e >= 0.f) ? e : 0.2f * e;
                sc += attv[j] * e;
            }
            const float p = __expf(sc);
            atomicAdd(&acc[ls][6], p);
#pragma unroll
            for (int j = 0; j < 6; j++)
                atomicAdd(&acc[ls][j], p * xls[j]);
        }
    }
    for (; i < e1; i += 256) {
        const int v0 = pairs[i];
        const int ls = v0 & 127;
        const uint4 g = xl4[((unsigned)v0) >> 7];
        float xls[6];
        xls[0] = __builtin_bit_cast(float, g.x << 16);
        xls[1] = __builtin_bit_cast(float, g.x & 0xffff0000u);
        xls[2] = __builtin_bit_cast(float, g.y << 16);
        xls[3] = __builtin_bit_cast(float, g.y & 0xffff0000u);
        xls[4] = __builtin_bit_cast(float, g.z << 16);
        xls[5] = __builtin_bit_cast(float, g.z & 0xffff0000u);
        float sc = 0.f;
#pragma unroll
        for (int j = 0; j < 6; j++) {
            float e = xls[j] + xrs[ls][j];
            e = (e >= 0.f) ? e : 0.2f * e;
            sc += attv[j] * e;
        }
        const float p = __expf(sc);
        atomicAdd(&acc[ls][6], p);
#pragma unroll
        for (int j = 0; j < 6; j++)
            atomicAdd(&acc[ls][j], p * xls[j]);
    }
    __syncthreads();

    // finalize node d0: self-loop + normalize + leaky + jk + pooled sum
    float h[4] = {0.f, 0.f, 0.f, 0.f};
    float cw = 0.f;
    int b = 0;
    if (t < BSZ && d0 < N_NODES) {
        const uint4 g = xl4[d0];
        float xld[6];
        xld[0] = __builtin_bit_cast(float, g.x << 16);
        xld[1] = __builtin_bit_cast(float, g.x & 0xffff0000u);
        xld[2] = __builtin_bit_cast(float, g.y << 16);
        xld[3] = __builtin_bit_cast(float, g.y & 0xffff0000u);
        xld[4] = __builtin_bit_cast(float, g.z << 16);
        xld[5] = __builtin_bit_cast(float, g.z & 0xffff0000u);
        float sc = 0.f;
#pragma unroll
        for (int j = 0; j < 6; j++) {
            float e = xld[j] + xrs[t][j];
            e = (e >= 0.f) ? e : 0.2f * e;
            sc += attv[j] * e;
        }
        const float p = __expf(sc);
        const float z = acc[t][6] + p;
#pragma unroll
        for (int c = 0; c < 4; c++) h[c] = jkb[c];
#pragma unroll
        for (int j = 0; j < 6; j++) {
            float aj = (acc[t][j] + p * xld[j]) / z + conv_b[j];
            aj = (aj >= 0.f) ? aj : 0.01f * aj;
#pragma unroll
            for (int c = 0; c < 4; c++) h[c] += aj * jkW[j * 4 + c];
        }
        b = batch[d0];
        cw = 1.f;
    }
    const int b0 = __shfl(b, 0);
    if (__all(b == b0)) {
#pragma unroll
        for (int off = 32; off >= 1; off >>= 1) {
#pragma unroll
            for (int c = 0; c < 4; c++) h[c] += __shfl_xor(h[c], off);
            cw += __shfl_xor(cw, off);
        }
        if ((t & 63) == 0 && cw > 0.f) {
#pragma unroll
            for (int c = 0; c < 4; c++) atomicAdd(gsum + b0 * 4 + c, h[c]);
            atomicAdd(gcnt + b0, cw);
        }
    } else if (cw > 0.f) {
#pragma unroll
        for (int c = 0; c < 4; c++) atomicAdd(gsum + b * 4 + c, h[c]);
        atomicAdd(gcnt + b, cw);
    }
}

// cast-transpose W[K][N] f32 -> Wt[N][K] bf16
__global__ __launch_bounds__(256) void castT(
    const float* __restrict__ W, unsigned short* __restrict__ Wt, int K, int N)
{
    const int k = blockIdx.x * 256 + threadIdx.x;
    const int n = blockIdx.y;
    if (k < K) Wt[(size_t)n * K + k] = bf16rne(W[(size_t)k * N + n]);
}

// C[M,N] = A[M,K] @ Bt[N,K]^T + bias, bf16 MFMA 16x16x32, fp32 accumulate.
// Block 256 thr (4 waves), tile BM=32 x BN, BK=64. LDS chunk-XOR swizzle.
// A staged fp32->bf16 in-register (ABF16=false) or via global_load_lds (true);
// B always via global_load_lds 16B.
template<int BN, bool ABF16>
__global__ __launch_bounds__(256) void mfma_gemm(
    const void* __restrict__ Asrc, const unsigned short* __restrict__ Bt,
    const float* __restrict__ bias, float* __restrict__ C,
    int M, int N, int K)
{
    constexpr int WN = BN / 4;        // wave column span
    constexpr int NFR = BN / 64;      // 16-wide n-frags per wave
    __shared__ unsigned short As[32 * 64];
    __shared__ unsigned short Bs[BN * 64];
    const int t = threadIdx.x;
    const int w = t >> 6, l = t & 63;
    const int l15 = l & 15, quad = l >> 4;
    const int gm0 = blockIdx.x * 32;
    const int gn0 = blockIdx.y * BN;
    const int r8 = l >> 3;            // 0..7 row within a 1KB cp chunk
    const int c8 = (l & 7) ^ r8;      // swizzled k-chunk this lane fetches

    f32x4 acc[2][NFR];
#pragma unroll
    for (int mt = 0; mt < 2; mt++)
#pragma unroll
        for (int nt = 0; nt < NFR; nt++) acc[mt][nt] = (f32x4){0.f, 0.f, 0.f, 0.f};

    for (int k0 = 0; k0 < K; k0 += 64) {
        // B tile: BN/8 async 1KB copies, BN/32 per wave
#pragma unroll
        for (int c = 0; c < BN / 32; c++) {
            const int j = w * (BN / 32) + c;
            async_cp16(Bt + (size_t)(gn0 + j * 8 + r8) * K + k0 + c8 * 8,
                       &Bs[j * 512]);
        }
        if constexpr (ABF16) {
            async_cp16((const unsigned short*)Asrc +
                           (size_t)(gm0 + w * 8 + r8) * K + k0 + c8 * 8,
                       &As[w * 512]);
        } else {
            const float* Af = (const float*)Asrc;
            const int ar = t >> 3, ac = t & 7;     // row 0..31, chunk 0..7
            const float* src = Af + (size_t)(gm0 + ar) * K + k0 + ac * 8;
            float4 v0 = *(const float4*)src;
            float4 v1 = *(const float4*)(src + 4);
            union { unsigned short h[8]; uint4 v; } u;
            u.h[0] = bf16rne(v0.x); u.h[1] = bf16rne(v0.y);
            u.h[2] = bf16rne(v0.z); u.h[3] = bf16rne(v0.w);
            u.h[4] = bf16rne(v1.x); u.h[5] = bf16rne(v1.y);
            u.h[6] = bf16rne(v1.z); u.h[7] = bf16rne(v1.w);
            *(uint4*)&As[ar * 64 + (ac ^ (ar & 7)) * 8] = u.v;
        }
        __syncthreads();   // drains vmcnt (async copies) + lgkm, then barrier
#pragma unroll
        for (int kki = 0; kki < 2; kki++) {
            bf16x8 af[2], bfr[NFR];
#pragma unroll
            for (int mt = 0; mt < 2; mt++) {
                const int m = mt * 16 + l15;
                af[mt] = *(const bf16x8*)&As[m * 64 + (((quad + 4 * kki) ^ (m & 7)) * 8)];
            }
#pragma unroll
            for (int nt = 0; nt < NFR; nt++) {
                const int n = w * WN + nt * 16 + l15;
                bfr[nt] = *(const bf16x8*)&Bs[n * 64 + (((quad + 4 * kki) ^ (n & 7)) * 8)];
            }
#pragma unroll
            for (int mt = 0; mt < 2; mt++)
#pragma unroll
                for (int nt = 0; nt < NFR; nt++)
                    acc[mt][nt] = __builtin_amdgcn_mfma_f32_16x16x32_bf16(
                        af[mt], bfr[nt], acc[mt][nt], 0, 0, 0);
        }
        __syncthreads();
    }
#pragma unroll
    for (int nt = 0; nt < NFR; nt++) {
        const int col = gn0 + w * WN + nt * 16 + l15;
        const float bv = bias[col];
#pragma unroll
        for (int mt = 0; mt < 2; mt++)
#pragma unroll
            for (int rr = 0; rr < 4; rr++) {
                const int row = gm0 + mt * 16 + quad * 4 + rr;
                C[(size_t)row * N + col] = acc[mt][nt][rr] + bv;
            }
    }
}

// LayerNorm(C=256) + leaky(0.01), f32 in -> bf16 out. One block per row.
__global__ __launch_bounds__(256) void ln_leaky_c256(
    const float* __restrict__ f, unsigned short* __restrict__ out,
    const float* __restrict__ g, const float* __restrict__ b)
{
    const int row = blockIdx.x;
    const int t = threadIdx.x;
    float v = f[(size_t)row * 256 + t];
    float s = v, s2 = v * v;
#pragma unroll
    for (int off = 32; off >= 1; off >>= 1) {
        s += __shfl_xor(s, off);
        s2 += __shfl_xor(s2, off);
    }
    __shared__ float ws[4], ws2[4];
    const int wid = t >> 6, lane = t & 63;
    if (lane == 0) { ws[wid] = s; ws2[wid] = s2; }
    __syncthreads();
    const float S = ws[0] + ws[1] + ws[2] + ws[3];
    const float S2 = ws2[0] + ws2[1] + ws2[2] + ws2[3];
    const float mu = S * (1.0f / 256.0f);
    const float var = S2 * (1.0f / 256.0f) - mu * mu;
    float y = (v - mu) * rsqrtf(var + 1e-5f) * g[t] + b[t];
    y = (y >= 0.f) ? y : 0.01f * y;
    out[(size_t)row * 256 + t] = bf16rne(y);
}

// In-place LayerNorm(C=64) + leaky(0.01). One wave per row, 4 rows/block.
__global__ __launch_bounds__(256) void ln_leaky_c64(
    float* __restrict__ f, const float* __restrict__ g, const float* __restrict__ b)
{
    const int wid = threadIdx.x >> 6, lane = threadIdx.x & 63;
    const int row = blockIdx.x * 4 + wid;
    float v = f[(size_t)row * 64 + lane];
    float s = v, s2 = v * v;
#pragma unroll
    for (int off = 32; off >= 1; off >>= 1) {
        s += __shfl_xor(s, off);
        s2 += __shfl_xor(s2, off);
    }
    const float mu = s * (1.0f / 64.0f);
    const float var = s2 * (1.0f / 64.0f) - mu * mu;
    float y = (v - mu) * rsqrtf(var + 1e-5f) * g[lane] + b[lane];
    f[(size_t)row * 64 + lane] = (y >= 0.f) ? y : 0.01f * y;
}

// f3 = leaky(LN(f2 @ W3 + b3)).  8 threads per row.
__global__ __launch_bounds__(256) void l3_ln_leaky(
    const float* __restrict__ f2, const float* __restrict__ W3,
    const float* __restrict__ b3,
    const float* __restrict__ g, const float* __restrict__ b,
    float* __restrict__ f3)
{
    __shared__ float sW[64 * 8];
    const int t = threadIdx.x;
    sW[t] = W3[t]; sW[t + 256] = W3[t + 256];
    __syncthreads();
    const int row = blockIdx.x * 32 + (t >> 3);
    const int c = t & 7;
    float acc = b3[c];
    const float* fr = f2 + (size_t)row * 64;
#pragma unroll 8
    for (int k = 0; k < 64; k++) acc += fr[k] * sW[k * 8 + c];
    float s = acc, s2 = acc * acc;
#pragma unroll
    for (int off = 4; off >= 1; off >>= 1) {
        s += __shfl_xor(s, off);
        s2 += __shfl_xor(s2, off);
    }
    const float mu = s * (1.0f / 8.0f);
    const float var = s2 * (1.0f / 8.0f) - mu * mu;
    float y = (acc - mu) * rsqrtf(var + 1e-5f) * g[c] + b[c];
    f3[(size_t)row * 8 + c] = (y >= 0.f) ? y : 0.01f * y;
}

// xf = leaky(LN(flat @ fl_W + fl_b)). One block per graph.
__global__ __launch_bounds__(256) void flat_ln_leaky(
    const float* __restrict__ f3, const float* __restrict__ W,
    const float* __restrict__ bb,
    const float* __restrict__ g, const float* __restrict__ b,
    float* __restrict__ xf)
{
    __shared__ float sf[1024];
    __shared__ float sp[8][32];
    const int t = threadIdx.x;
    const int gb = blockIdx.x;
    *(float4*)&sf[t * 4] = *(const float4*)(f3 + (size_t)gb * 1024 + t * 4);
    __syncthreads();
    const int c = t & 31, part = t >> 5;
    float acc = 0.f;
    for (int k = part * 128; k < part * 128 + 128; k++) acc += sf[k] * W[k * 32 + c];
    sp[part][c] = acc;
    __syncthreads();
    if (t < 32) {
        float v = bb[t];
#pragma unroll
        for (int p = 0; p < 8; p++) v += sp[p][t];
        float s = v, s2 = v * v;
#pragma unroll
        for (int off = 16; off >= 1; off >>= 1) {
            s += __shfl_xor(s, off);
            s2 += __shfl_xor(s2, off);
        }
        const float mu = s * (1.0f / 32.0f);
        const float var = s2 * (1.0f / 32.0f) - mu * mu;
        float y = (v - mu) * rsqrtf(var + 1e-5f) * g[t] + b[t];
        xf[gb * 32 + t] = (y >= 0.f) ? y : 0.01f * y;
    }
}

// out[b,o] = cat(gsum/cnt, xf, one_hot) @ out_W + out_b
__global__ __launch_bounds__(128) void final_out(
    const float* __restrict__ gsum, const float* __restrict__ gcnt,
    const float* __restrict__ xf, const float* __restrict__ onehot,
    const float* __restrict__ Wo, const float* __restrict__ bo,
    float* __restrict__ out)
{
    const int t = threadIdx.x;
    const int gb = t >> 1, o = t & 1;
    float cnt = gcnt[gb];
    cnt = (cnt > 1.f) ? cnt : 1.f;
    float acc = bo[o];
#pragma unroll
    for (int j = 0; j < 4; j++)  acc += (gsum[gb * 4 + j] / cnt) * Wo[j * 2 + o];
#pragma unroll
    for (int j = 0; j < 32; j++) acc += xf[gb * 32 + j] * Wo[(4 + j) * 2 + o];
#pragma unroll
    for (int j = 0; j < 20; j++) acc += onehot[gb * 20 + j] * Wo[(36 + j) * 2 + o];
    out[t] = acc;
}

extern "C" void kernel_launch(void* const* d_in, const int* in_sizes, int n_in,
                              void* d_out, int out_size, void* d_ws, size_t ws_size,
                              hipStream_t stream)
{
    const float* x        = (const float*)d_in[0];
    const int*   ei       = (const int*)d_in[1];
    const int*   batch    = (const int*)d_in[2];
    const float* features = (const float*)d_in[3];
    const float* one_hot  = (const float*)d_in[4];
    const float* W_l   = (const float*)d_in[5];
    const float* b_l   = (const float*)d_in[6];
    const float* W_r   = (const float*)d_in[7];
    const float* b_r   = (const float*)d_in[8];
    const float* att   = (const float*)d_in[9];
    const float* conv_b = (const float*)d_in[10];
    const float* jk_W  = (const float*)d_in[11];
    const float* jk_b  = (const float*)d_in[12];
    const float* l1_W  = (const float*)d_in[13];
    const float* l1_b  = (const float*)d_in[14];
    const float* ln1_g = (const float*)d_in[15];
    const float* ln1_b = (const float*)d_in[16];
    const float* l2_W  = (const float*)d_in[17];
    const float* l2_b  = (const float*)d_in[18];
    const float* ln2_g = (const float*)d_in[19];
    const float* ln2_b = (const float*)d_in[20];
    const float* l3_W  = (const float*)d_in[21];
    const float* l3_b  = (const float*)d_in[22];
    const float* ln3_g = (const float*)d_in[23];
    const float* ln3_b = (const float*)d_in[24];
    const float* fl_W  = (const float*)d_in[25];
    const float* fl_b  = (const float*)d_in[26];
    const float* ln4_g = (const float*)d_in[27];
    const float* ln4_b = (const float*)d_in[28];
    const float* out_W = (const float*)d_in[29];
    const float* out_b = (const float*)d_in[30];
    (void)in_sizes; (void)n_in; (void)out_size; (void)ws_size;

    float* ws = (float*)d_ws;
    unsigned short* xlb = (unsigned short*)(ws + 0);
    float* xr   = ws + 800000;
    unsigned short* w1t = (unsigned short*)(ws + 2400000);
    unsigned short* w2t = (unsigned short*)(ws + 2727680);
    float* gsum = ws + 2735872;
    float* gcnt = ws + 2736128;
    // edge-phase scratch (aliased over MLP scratch)
    int* bstart = (int*)(ws + 2736192);
    int* bhist  = (int*)(ws + 2737756);
    int* bofs   = (int*)(ws + 2937820);
    int* pairs  = (int*)(ws + 3137884);
    // MLP scratch (valid after bucket_reduce completes)
    float* f1           = ws + 2736192;
    unsigned short* f1b = (unsigned short*)(ws + 4833344);
    float* f2           = ws + 5881920;
    float* f3           = ws + 6406208;
    float* xf           = ws + 6471744;

    hipMemsetAsync(gsum, 0, 320 * sizeof(float), stream);

    node_xform<<<N_NODES / 16, 256, 0, stream>>>(x, W_l, b_l, W_r, b_r, xlb, xr);
    edge_hist<<<HBLK, 256, 0, stream>>>(ei, bhist);
    edge_scan<<<1, 1024, 0, stream>>>(bhist, bofs, bstart);
    edge_scatter<<<HBLK, 256, 0, stream>>>(ei, bofs, pairs);
    castT<<<dim3(10, 256), 256, 0, stream>>>(l1_W, w1t, FEAT, 256);
    castT<<<dim3(1, 64), 256, 0, stream>>>(l2_W, w2t, 256, 64);
    bucket_reduce<<<NBK, 256, 0, stream>>>(pairs, bstart, xlb, xr, att, conv_b,
                                           jk_W, jk_b, batch, gsum, gcnt);
    mfma_gemm<128, false><<<dim3(MROWS / 32, 2), 256, 0, stream>>>(
        features, w1t, l1_b, f1, MROWS, 256, FEAT);
    ln_leaky_c256<<<MROWS, 256, 0, stream>>>(f1, f1b, ln1_g, ln1_b);
    mfma_gemm<64, true><<<dim3(MROWS / 32, 1), 256, 0, stream>>>(
        f1b, w2t, l2_b, f2, MROWS, 64, 256);
    ln_leaky_c64<<<MROWS / 4, 256, 0, stream>>>(f2, ln2_g, ln2_b);
    l3_ln_leaky<<<MROWS / 32, 256, 0, stream>>>(f2, l3_W, l3_b, ln3_g, ln3_b, f3);
    flat_ln_leaky<<<NB, 256, 0, stream>>>(f3, fl_W, fl_b, ln4_g, ln4_b, xf);
    final_out<<<1, 128, 0, stream>>>(gsum, gcnt, xf, one_hot, out_W, out_b, (float*)d_out);
}

// Round 4
// 728.452 us; speedup vs baseline: 3.8441x; 1.3305x over previous
//
#include <hip/hip_runtime.h>
#include <cstdint>
#include <cstddef>

#define N_NODES 200000
#define N_EDGES 6400000
#define NB      64
#define MROWS   8192     // NB*ROWS
#define FEAT    2560

// edge bucketing: bucket = 256 consecutive dst nodes
#define BSZ   256
#define NBK   782        // ceil(200000/256)
#define HBLK  128        // histogram/scatter blocks
#define ETILE 50000      // edges per block (HBLK*ETILE == N_EDGES)
#define CAP   8960       // in-LDS sort capacity per chunk (mean 8192, sd ~90)

typedef __attribute__((ext_vector_type(8))) short bf16x8;
typedef __attribute__((ext_vector_type(4))) float f32x4;

__device__ __forceinline__ unsigned short bf16rne(float f) {
    unsigned u = __builtin_bit_cast(unsigned, f);
    u += 0x7fffu + ((u >> 16) & 1u);
    return (unsigned short)(u >> 16);
}

__device__ __forceinline__ void async_cp16(const void* g, void* l) {
    __builtin_amdgcn_global_load_lds(
        (const __attribute__((address_space(1))) unsigned int*)g,
        (__attribute__((address_space(3))) unsigned int*)l, 16, 0, 0);
}

// unpack bf16x6 gather, accumulate one edge into register z/agg
__device__ __forceinline__ void edge_acc(
    uint4 g, const float* xrd, const float* attv, float& z, float* agg)
{
    float xls[6];
    xls[0] = __builtin_bit_cast(float, g.x << 16);
    xls[1] = __builtin_bit_cast(float, g.x & 0xffff0000u);
    xls[2] = __builtin_bit_cast(float, g.y << 16);
    xls[3] = __builtin_bit_cast(float, g.y & 0xffff0000u);
    xls[4] = __builtin_bit_cast(float, g.z << 16);
    xls[5] = __builtin_bit_cast(float, g.z & 0xffff0000u);
    float sc = 0.f;
#pragma unroll
    for (int j = 0; j < 6; j++) {
        float e = xls[j] + xrd[j];
        e = (e >= 0.f) ? e : 0.2f * e;
        sc += attv[j] * e;
    }
    const float p = __expf(sc);
    z += p;
#pragma unroll
    for (int j = 0; j < 6; j++) agg[j] += p * xls[j];
}

// ---------------------------------------------------------------------------
// Workspace layout (4-byte units), edge scratch aliased over MLP scratch:
//   xlb  (bf16[200000][8])   @ 0
//   xr   (f32 [200000][8])   @ 800,000
//   w1t  (bf16[256][2560])   @ 2,400,000
//   w2t  (bf16[64][256])     @ 2,727,680
//   gsum [256] @ 2,735,872 ; gcnt [64] @ 2,736,128  (memset 320)
//   union @ 2,736,192:
//     edge: bstart[800] @2,736,192; bhist[128*782] @2,736,992;
//           bofs @2,837,088; pairs[6.4M] @2,937,184 .. 9,337,184  (37.3 MB)
//     mlp:  f1 f32[8192*256] @2,736,192; f1b bf16 @4,833,344;
//           f2 @5,881,920; f3 @6,406,208; xf @6,471,744
// ---------------------------------------------------------------------------

// xl (bf16 packed, 16B/node) and xr (f32, stride 8) node transforms.
__global__ __launch_bounds__(256) void node_xform(
    const float* __restrict__ x,
    const float* __restrict__ Wl, const float* __restrict__ bl,
    const float* __restrict__ Wr, const float* __restrict__ br,
    unsigned short* __restrict__ xlb, float* __restrict__ xr)
{
    const int t = threadIdx.x;
    const int l = t & 15;
    const int node = blockIdx.x * 16 + (t >> 4);

    float wl[48], wr[48];
#pragma unroll
    for (int q = 0; q < 12; q++) {
        *(float4*)&wl[q * 4] = *(const float4*)(Wl + 48 * l + 4 * q);
        *(float4*)&wr[q * 4] = *(const float4*)(Wr + 48 * l + 4 * q);
    }
    float xv[8];
    *(float4*)&xv[0] = *(const float4*)(x + (size_t)node * 128 + l * 8);
    *(float4*)&xv[4] = *(const float4*)(x + (size_t)node * 128 + l * 8 + 4);

    float al[6] = {}, ar[6] = {};
#pragma unroll
    for (int i = 0; i < 8; i++) {
#pragma unroll
        for (int j = 0; j < 6; j++) {
            al[j] += xv[i] * wl[i * 6 + j];
            ar[j] += xv[i] * wr[i * 6 + j];
        }
    }
#pragma unroll
    for (int off = 8; off >= 1; off >>= 1) {
#pragma unroll
        for (int j = 0; j < 6; j++) {
            al[j] += __shfl_xor(al[j], off);
            ar[j] += __shfl_xor(ar[j], off);
        }
    }
    if (l == 0) {
        union { unsigned short h[8]; uint4 v; } u;
#pragma unroll
        for (int j = 0; j < 6; j++) u.h[j] = bf16rne(al[j] + bl[j]);
        u.h[6] = 0; u.h[7] = 0;
        *(uint4*)(xlb + (size_t)node * 8) = u.v;
        float4 r0; float2 r1;
        r0.x = ar[0] + br[0]; r0.y = ar[1] + br[1];
        r0.z = ar[2] + br[2]; r0.w = ar[3] + br[3];
        r1.x = ar[4] + br[4]; r1.y = ar[5] + br[5];
        *(float4*)(xr + (size_t)node * 8) = r0;
        *(float2*)(xr + (size_t)node * 8 + 4) = r1;
    }
}

// Pass 1: per-block LDS histogram of dst buckets.
__global__ __launch_bounds__(256) void edge_hist(
    const int* __restrict__ ei, int* __restrict__ bhist)
{
    __shared__ int h[NBK];
    for (int i = threadIdx.x; i < NBK; i += 256) h[i] = 0;
    __syncthreads();
    const int base = blockIdx.x * ETILE;
    const int end = base + ETILE;
    for (int i = base + threadIdx.x; i < end; i += 256)
        atomicAdd(&h[ei[N_EDGES + i] >> 8], 1);
    __syncthreads();
    for (int i = threadIdx.x; i < NBK; i += 256)
        bhist[blockIdx.x * NBK + i] = h[i];
}

// Pass 2: bucket bases + per-(block,bucket) scatter offsets. One block.
__global__ __launch_bounds__(1024) void edge_scan(
    const int* __restrict__ bhist, int* __restrict__ bofs, int* __restrict__ bstart)
{
    __shared__ int colsum[NBK];
    __shared__ int basev[NBK];
    const int t = threadIdx.x;
    for (int b = t; b < NBK; b += 1024) {
        int s = 0;
        for (int blk = 0; blk < HBLK; blk++) s += bhist[blk * NBK + b];
        colsum[b] = s;
    }
    __syncthreads();
    if (t == 0) {
        int run = 0;
        for (int b = 0; b < NBK; b++) { basev[b] = run; run += colsum[b]; }
        bstart[NBK] = N_EDGES;
    }
    __syncthreads();
    for (int b = t; b < NBK; b += 1024) {
        int run = basev[b];
        bstart[b] = run;
        for (int blk = 0; blk < HBLK; blk++) {
            bofs[blk * NBK + b] = run;
            run += bhist[blk * NBK + b];
        }
    }
}

// Pass 3: scatter edges into bucket-contiguous order. pairs = src<<8 | dst&255.
__global__ __launch_bounds__(256) void edge_scatter(
    const int* __restrict__ ei, const int* __restrict__ bofs, int* __restrict__ pairs)
{
    __shared__ int cnt[NBK];
    for (int i = threadIdx.x; i < NBK; i += 256)
        cnt[i] = bofs[blockIdx.x * NBK + i];
    __syncthreads();
    const int base = blockIdx.x * ETILE;
    const int end = base + ETILE;
    for (int i = base + threadIdx.x; i < end; i += 256) {
        const int d = ei[N_EDGES + i];
        const int s = ei[i];
        const int pos = atomicAdd(&cnt[d >> 8], 1);
        pairs[pos] = (s << 8) | (d & 255);
    }
}

// Pass 4: one block per 256-node bucket. In-LDS counting sort by local dst,
// then thread t owns dst t: walks its contiguous run, accumulates in REGISTERS
// (no accumulation atomics). Fused finalize + jk + pooled segment-mean.
__global__ __launch_bounds__(256) void bucket_reduce(
    const int* __restrict__ pairs, const int* __restrict__ bstart,
    const unsigned short* __restrict__ xlb, const float* __restrict__ xr,
    const float* __restrict__ att, const float* __restrict__ conv_b,
    const float* __restrict__ jkW, const float* __restrict__ jkb,
    const int* __restrict__ batch,
    float* __restrict__ gsum, float* __restrict__ gcnt)
{
    __shared__ int sorted[CAP];
    __shared__ int hist[256];     // histogram, then scatter cursor
    __shared__ int wtot[4];
    const int t = threadIdx.x;
    const int lane = t & 63, wid = t >> 6;
    const int d0 = blockIdx.x * BSZ + t;

    float xrd[6];
    if (d0 < N_NODES) {
        float4 a = *(const float4*)(xr + (size_t)d0 * 8);
        float2 b = *(const float2*)(xr + (size_t)d0 * 8 + 4);
        xrd[0] = a.x; xrd[1] = a.y; xrd[2] = a.z;
        xrd[3] = a.w; xrd[4] = b.x; xrd[5] = b.y;
    } else {
#pragma unroll
        for (int j = 0; j < 6; j++) xrd[j] = 0.f;
    }
    float attv[6];
#pragma unroll
    for (int j = 0; j < 6; j++) attv[j] = att[j];

    float z = 0.f, agg[6] = {};
    const uint4* xl4 = (const uint4*)xlb;
    const int e0 = bstart[blockIdx.x], e1 = bstart[blockIdx.x + 1];

    for (int c0 = e0; c0 < e1; c0 += CAP) {
        const int rem = e1 - c0;
        const int cnt_chunk = (rem < CAP) ? rem : CAP;
        hist[t] = 0;
        __syncthreads();
        for (int i = t; i < cnt_chunk; i += 256)
            atomicAdd(&hist[pairs[c0 + i] & 255], 1);
        __syncthreads();
        // exclusive prefix: wave shfl-scan + cross-wave offsets
        const int h = hist[t];
        int v = h;
#pragma unroll
        for (int d = 1; d < 64; d <<= 1) {
            int o = __shfl_up(v, d);
            if (lane >= d) v += o;
        }
        if (lane == 63) wtot[wid] = v;
        __syncthreads();
        int off = 0;
#pragma unroll
        for (int wv = 0; wv < 3; wv++) if (wv < wid) off += wtot[wv];
        const int my_start = v - h + off;
        const int my_cnt = h;
        __syncthreads();
        hist[t] = my_start;        // becomes scatter cursor
        __syncthreads();
        for (int i = t; i < cnt_chunk; i += 256) {
            const int pv = pairs[c0 + i];
            const int pos = atomicAdd(&hist[pv & 255], 1);
            sorted[pos] = ((unsigned)pv) >> 8;
        }
        __syncthreads();
        // walk my run: 4-wide batched gathers (independent -> pipelined)
        int i = 0;
        for (; i + 4 <= my_cnt; i += 4) {
            const int s0 = sorted[my_start + i];
            const int s1 = sorted[my_start + i + 1];
            const int s2 = sorted[my_start + i + 2];
            const int s3 = sorted[my_start + i + 3];
            const uint4 g0 = xl4[s0], g1 = xl4[s1], g2 = xl4[s2], g3 = xl4[s3];
            edge_acc(g0, xrd, attv, z, agg);
            edge_acc(g1, xrd, attv, z, agg);
            edge_acc(g2, xrd, attv, z, agg);
            edge_acc(g3, xrd, attv, z, agg);
        }
        for (; i < my_cnt; i++) {
            const uint4 g = xl4[sorted[my_start + i]];
            edge_acc(g, xrd, attv, z, agg);
        }
        __syncthreads();           // LDS reused next chunk
    }

    // finalize node d0: self-loop + normalize + leaky + jk + pooled sum
    float hh[4] = {0.f, 0.f, 0.f, 0.f};
    float cw = 0.f;
    int b = 0;
    if (d0 < N_NODES) {
        const uint4 g = xl4[d0];
        float xld[6];
        xld[0] = __builtin_bit_cast(float, g.x << 16);
        xld[1] = __builtin_bit_cast(float, g.x & 0xffff0000u);
        xld[2] = __builtin_bit_cast(float, g.y << 16);
        xld[3] = __builtin_bit_cast(float, g.y & 0xffff0000u);
        xld[4] = __builtin_bit_cast(float, g.z << 16);
        xld[5] = __builtin_bit_cast(float, g.z & 0xffff0000u);
        float sc = 0.f;
#pragma unroll
        for (int j = 0; j < 6; j++) {
            float e = xld[j] + xrd[j];
            e = (e >= 0.f) ? e : 0.2f * e;
            sc += attv[j] * e;
        }
        const float p = __expf(sc);
        const float zz = z + p;
#pragma unroll
        for (int c = 0; c < 4; c++) hh[c] = jkb[c];
#pragma unroll
        for (int j = 0; j < 6; j++) {
            float aj = (agg[j] + p * xld[j]) / zz + conv_b[j];
            aj = (aj >= 0.f) ? aj : 0.01f * aj;
#pragma unroll
            for (int c = 0; c < 4; c++) hh[c] += aj * jkW[j * 4 + c];
        }
        b = batch[d0];
        cw = 1.f;
    }
    const int b0 = __shfl(b, 0);
    if (__all(b == b0)) {
#pragma unroll
        for (int off2 = 32; off2 >= 1; off2 >>= 1) {
#pragma unroll
            for (int c = 0; c < 4; c++) hh[c] += __shfl_xor(hh[c], off2);
            cw += __shfl_xor(cw, off2);
        }
        if (lane == 0 && cw > 0.f) {
#pragma unroll
            for (int c = 0; c < 4; c++) atomicAdd(gsum + b0 * 4 + c, hh[c]);
            atomicAdd(gcnt + b0, cw);
        }
    } else if (cw > 0.f) {
#pragma unroll
        for (int c = 0; c < 4; c++) atomicAdd(gsum + b * 4 + c, hh[c]);
        atomicAdd(gcnt + b, cw);
    }
}

// cast-transpose W[K][N] f32 -> Wt[N][K] bf16
__global__ __launch_bounds__(256) void castT(
    const float* __restrict__ W, unsigned short* __restrict__ Wt, int K, int N)
{
    const int k = blockIdx.x * 256 + threadIdx.x;
    const int n = blockIdx.y;
    if (k < K) Wt[(size_t)n * K + k] = bf16rne(W[(size_t)k * N + n]);
}

// L1 GEMM: C[M,256] = A[M,2560](f32) @ Bt[256,2560](bf16)^T + bias.
// BM=64, BN=128, BK=64; 4 waves 2x2; 16 MFMA/wave/iter; XOR-swizzled LDS.
__global__ __launch_bounds__(256) void mfma_gemm_l1(
    const float* __restrict__ A, const unsigned short* __restrict__ Bt,
    const float* __restrict__ bias, float* __restrict__ C,
    int M, int N, int K)
{
    __shared__ unsigned short As[64 * 64];
    __shared__ unsigned short Bs[128 * 64];
    const int t = threadIdx.x;
    const int w = t >> 6, l = t & 63;
    const int l15 = l & 15, quad = l >> 4;
    const int wm = (w & 1) * 32, wn = (w >> 1) * 64;
    const int gm0 = blockIdx.x * 64;
    const int gn0 = blockIdx.y * 128;
    const int r8 = l >> 3;
    const int c8 = (l & 7) ^ r8;
    // A staging coords: 4 threads/row, 2 chunks (16 elems) each
    const int ar = t >> 2;
    const int ac0 = (t & 3) * 2;

    f32x4 acc[2][4];
#pragma unroll
    for (int mt = 0; mt < 2; mt++)
#pragma unroll
        for (int nt = 0; nt < 4; nt++) acc[mt][nt] = (f32x4){0.f, 0.f, 0.f, 0.f};

    for (int k0 = 0; k0 < K; k0 += 64) {
        // B tile: 16 async 1KB chunks, 4 per wave
#pragma unroll
        for (int c = 0; c < 4; c++) {
            const int j = w * 4 + c;
            async_cp16(Bt + (size_t)(gn0 + j * 8 + r8) * K + k0 + c8 * 8,
                       &Bs[j * 512]);
        }
        // A tile: fp32 -> bf16 in-register, swizzled store
        {
            const float* src = A + (size_t)(gm0 + ar) * K + k0 + ac0 * 8;
            float4 v0 = *(const float4*)src;
            float4 v1 = *(const float4*)(src + 4);
            float4 v2 = *(const float4*)(src + 8);
            float4 v3 = *(const float4*)(src + 12);
            union { unsigned short h[8]; uint4 u; } p0, p1;
            p0.h[0] = bf16rne(v0.x); p0.h[1] = bf16rne(v0.y);
            p0.h[2] = bf16rne(v0.z); p0.h[3] = bf16rne(v0.w);
            p0.h[4] = bf16rne(v1.x); p0.h[5] = bf16rne(v1.y);
            p0.h[6] = bf16rne(v1.z); p0.h[7] = bf16rne(v1.w);
            p1.h[0] = bf16rne(v2.x); p1.h[1] = bf16rne(v2.y);
            p1.h[2] = bf16rne(v2.z); p1.h[3] = bf16rne(v2.w);
            p1.h[4] = bf16rne(v3.x); p1.h[5] = bf16rne(v3.y);
            p1.h[6] = bf16rne(v3.z); p1.h[7] = bf16rne(v3.w);
            *(uint4*)&As[ar * 64 + ((ac0 + 0) ^ (ar & 7)) * 8] = p0.u;
            *(uint4*)&As[ar * 64 + ((ac0 + 1) ^ (ar & 7)) * 8] = p1.u;
        }
        __syncthreads();
#pragma unroll
        for (int kki = 0; kki < 2; kki++) {
            bf16x8 af[2], bfr[4];
#pragma unroll
            for (int mt = 0; mt < 2; mt++) {
                const int m = wm + mt * 16 + l15;
                af[mt] = *(const bf16x8*)&As[m * 64 + (((quad + 4 * kki) ^ (m & 7)) * 8)];
            }
#pragma unroll
            for (int nt = 0; nt < 4; nt++) {
                const int n = wn + nt * 16 + l15;
                bfr[nt] = *(const bf16x8*)&Bs[n * 64 + (((quad + 4 * kki) ^ (n & 7)) * 8)];
            }
#pragma unroll
            for (int mt = 0; mt < 2; mt++)
#pragma unroll
                for (int nt = 0; nt < 4; nt++)
                    acc[mt][nt] = __builtin_amdgcn_mfma_f32_16x16x32_bf16(
                        af[mt], bfr[nt], acc[mt][nt], 0, 0, 0);
        }
        __syncthreads();
    }
#pragma unroll
    for (int nt = 0; nt < 4; nt++) {
        const int col = gn0 + wn + nt * 16 + l15;
        const float bv = bias[col];
#pragma unroll
        for (int mt = 0; mt < 2; mt++)
#pragma unroll
            for (int rr = 0; rr < 4; rr++) {
                const int row = gm0 + wm + mt * 16 + quad * 4 + rr;
                C[(size_t)row * N + col] = acc[mt][nt][rr] + bv;
            }
    }
}

// L2 GEMM (proven in R2): BM=32 x BN=64, A bf16 via async, Bt bf16.
__global__ __launch_bounds__(256) void mfma_gemm_l2(
    const unsigned short* __restrict__ Ab, const unsigned short* __restrict__ Bt,
    const float* __restrict__ bias, float* __restrict__ C,
    int M, int N, int K)
{
    __shared__ unsigned short As[32 * 64];
    __shared__ unsigned short Bs[64 * 64];
    const int t = threadIdx.x;
    const int w = t >> 6, l = t & 63;
    const int l15 = l & 15, quad = l >> 4;
    const int gm0 = blockIdx.x * 32;
    const int gn0 = blockIdx.y * 64;
    const int r8 = l >> 3;
    const int c8 = (l & 7) ^ r8;

    f32x4 acc[2];
    acc[0] = (f32x4){0.f, 0.f, 0.f, 0.f};
    acc[1] = (f32x4){0.f, 0.f, 0.f, 0.f};

    for (int k0 = 0; k0 < K; k0 += 64) {
#pragma unroll
        for (int c = 0; c < 2; c++) {
            const int j = w * 2 + c;
            async_cp16(Bt + (size_t)(gn0 + j * 8 + r8) * K + k0 + c8 * 8,
                       &Bs[j * 512]);
        }
        async_cp16(Ab + (size_t)(gm0 + w * 8 + r8) * K + k0 + c8 * 8, &As[w * 512]);
        __syncthreads();
#pragma unroll
        for (int kki = 0; kki < 2; kki++) {
            bf16x8 af[2], bfr;
#pragma unroll
            for (int mt = 0; mt < 2; mt++) {
                const int m = mt * 16 + l15;
                af[mt] = *(const bf16x8*)&As[m * 64 + (((quad + 4 * kki) ^ (m & 7)) * 8)];
            }
            const int n = w * 16 + l15;
            bfr = *(const bf16x8*)&Bs[n * 64 + (((quad + 4 * kki) ^ (n & 7)) * 8)];
#pragma unroll
            for (int mt = 0; mt < 2; mt++)
                acc[mt] = __builtin_amdgcn_mfma_f32_16x16x32_bf16(
                    af[mt], bfr, acc[mt], 0, 0, 0);
        }
        __syncthreads();
    }
    const int col = gn0 + w * 16 + l15;
    const float bv = bias[col];
#pragma unroll
    for (int mt = 0; mt < 2; mt++)
#pragma unroll
        for (int rr = 0; rr < 4; rr++) {
            const int row = gm0 + mt * 16 + quad * 4 + rr;
            C[(size_t)row * N + col] = acc[mt][rr] + bv;
        }
}

// LayerNorm(C=256) + leaky(0.01), f32 in -> bf16 out. One block per row.
__global__ __launch_bounds__(256) void ln_leaky_c256(
    const float* __restrict__ f, unsigned short* __restrict__ out,
    const float* __restrict__ g, const float* __restrict__ b)
{
    const int row = blockIdx.x;
    const int t = threadIdx.x;
    float v = f[(size_t)row * 256 + t];
    float s = v, s2 = v * v;
#pragma unroll
    for (int off = 32; off >= 1; off >>= 1) {
        s += __shfl_xor(s, off);
        s2 += __shfl_xor(s2, off);
    }
    __shared__ float ws[4], ws2[4];
    const int wid = t >> 6, lane = t & 63;
    if (lane == 0) { ws[wid] = s; ws2[wid] = s2; }
    __syncthreads();
    const float S = ws[0] + ws[1] + ws[2] + ws[3];
    const float S2 = ws2[0] + ws2[1] + ws2[2] + ws2[3];
    const float mu = S * (1.0f / 256.0f);
    const float var = S2 * (1.0f / 256.0f) - mu * mu;
    float y = (v - mu) * rsqrtf(var + 1e-5f) * g[t] + b[t];
    y = (y >= 0.f) ? y : 0.01f * y;
    out[(size_t)row * 256 + t] = bf16rne(y);
}

// In-place LayerNorm(C=64) + leaky(0.01). One wave per row, 4 rows/block.
__global__ __launch_bounds__(256) void ln_leaky_c64(
    float* __restrict__ f, const float* __restrict__ g, const float* __restrict__ b)
{
    const int wid = threadIdx.x >> 6, lane = threadIdx.x & 63;
    const int row = blockIdx.x * 4 + wid;
    float v = f[(size_t)row * 64 + lane];
    float s = v, s2 = v * v;
#pragma unroll
    for (int off = 32; off >= 1; off >>= 1) {
        s += __shfl_xor(s, off);
        s2 += __shfl_xor(s2, off);
    }
    const float mu = s * (1.0f / 64.0f);
    const float var = s2 * (1.0f / 64.0f) - mu * mu;
    float y = (v - mu) * rsqrtf(var + 1e-5f) * g[lane] + b[lane];
    f[(size_t)row * 64 + lane] = (y >= 0.f) ? y : 0.01f * y;
}

// f3 = leaky(LN(f2 @ W3 + b3)).  8 threads per row.
__global__ __launch_bounds__(256) void l3_ln_leaky(
    const float* __restrict__ f2, const float* __restrict__ W3,
    const float* __restrict__ b3,
    const float* __restrict__ g, const float* __restrict__ b,
    float* __restrict__ f3)
{
    __shared__ float sW[64 * 8];
    const int t = threadIdx.x;
    sW[t] = W3[t]; sW[t + 256] = W3[t + 256];
    __syncthreads();
    const int row = blockIdx.x * 32 + (t >> 3);
    const int c = t & 7;
    float acc = b3[c];
    const float* fr = f2 + (size_t)row * 64;
#pragma unroll 8
    for (int k = 0; k < 64; k++) acc += fr[k] * sW[k * 8 + c];
    float s = acc, s2 = acc * acc;
#pragma unroll
    for (int off = 4; off >= 1; off >>= 1) {
        s += __shfl_xor(s, off);
        s2 += __shfl_xor(s2, off);
    }
    const float mu = s * (1.0f / 8.0f);
    const float var = s2 * (1.0f / 8.0f) - mu * mu;
    float y = (acc - mu) * rsqrtf(var + 1e-5f) * g[c] + b[c];
    f3[(size_t)row * 8 + c] = (y >= 0.f) ? y : 0.01f * y;
}

// xf = leaky(LN(flat @ fl_W + fl_b)). One block per graph.
__global__ __launch_bounds__(256) void flat_ln_leaky(
    const float* __restrict__ f3, const float* __restrict__ W,
    const float* __restrict__ bb,
    const float* __restrict__ g, const float* __restrict__ b,
    float* __restrict__ xf)
{
    __shared__ float sf[1024];
    __shared__ float sp[8][32];
    const int t = threadIdx.x;
    const int gb = blockIdx.x;
    *(float4*)&sf[t * 4] = *(const float4*)(f3 + (size_t)gb * 1024 + t * 4);
    __syncthreads();
    const int c = t & 31, part = t >> 5;
    float acc = 0.f;
    for (int k = part * 128; k < part * 128 + 128; k++) acc += sf[k] * W[k * 32 + c];
    sp[part][c] = acc;
    __syncthreads();
    if (t < 32) {
        float v = bb[t];
#pragma unroll
        for (int p = 0; p < 8; p++) v += sp[p][t];
        float s = v, s2 = v * v;
#pragma unroll
        for (int off = 16; off >= 1; off >>= 1) {
            s += __shfl_xor(s, off);
            s2 += __shfl_xor(s2, off);
        }
        const float mu = s * (1.0f / 32.0f);
        const float var = s2 * (1.0f / 32.0f) - mu * mu;
        float y = (v - mu) * rsqrtf(var + 1e-5f) * g[t] + b[t];
        xf[gb * 32 + t] = (y >= 0.f) ? y : 0.01f * y;
    }
}

// out[b,o] = cat(gsum/cnt, xf, one_hot) @ out_W + out_b
__global__ __launch_bounds__(128) void final_out(
    const float* __restrict__ gsum, const float* __restrict__ gcnt,
    const float* __restrict__ xf, const float* __restrict__ onehot,
    const float* __restrict__ Wo, const float* __restrict__ bo,
    float* __restrict__ out)
{
    const int t = threadIdx.x;
    const int gb = t >> 1, o = t & 1;
    float cnt = gcnt[gb];
    cnt = (cnt > 1.f) ? cnt : 1.f;
    float acc = bo[o];
#pragma unroll
    for (int j = 0; j < 4; j++)  acc += (gsum[gb * 4 + j] / cnt) * Wo[j * 2 + o];
#pragma unroll
    for (int j = 0; j < 32; j++) acc += xf[gb * 32 + j] * Wo[(4 + j) * 2 + o];
#pragma unroll
    for (int j = 0; j < 20; j++) acc += onehot[gb * 20 + j] * Wo[(36 + j) * 2 + o];
    out[t] = acc;
}

extern "C" void kernel_launch(void* const* d_in, const int* in_sizes, int n_in,
                              void* d_out, int out_size, void* d_ws, size_t ws_size,
                              hipStream_t stream)
{
    const float* x        = (const float*)d_in[0];
    const int*   ei       = (const int*)d_in[1];
    const int*   batch    = (const int*)d_in[2];
    const float* features = (const float*)d_in[3];
    const float* one_hot  = (const float*)d_in[4];
    const float* W_l   = (const float*)d_in[5];
    const float* b_l   = (const float*)d_in[6];
    const float* W_r   = (const float*)d_in[7];
    const float* b_r   = (const float*)d_in[8];
    const float* att   = (const float*)d_in[9];
    const float* conv_b = (const float*)d_in[10];
    const float* jk_W  = (const float*)d_in[11];
    const float* jk_b  = (const float*)d_in[12];
    const float* l1_W  = (const float*)d_in[13];
    const float* l1_b  = (const float*)d_in[14];
    const float* ln1_g = (const float*)d_in[15];
    const float* ln1_b = (const float*)d_in[16];
    const float* l2_W  = (const float*)d_in[17];
    const float* l2_b  = (const float*)d_in[18];
    const float* ln2_g = (const float*)d_in[19];
    const float* ln2_b = (const float*)d_in[20];
    const float* l3_W  = (const float*)d_in[21];
    const float* l3_b  = (const float*)d_in[22];
    const float* ln3_g = (const float*)d_in[23];
    const float* ln3_b = (const float*)d_in[24];
    const float* fl_W  = (const float*)d_in[25];
    const float* fl_b  = (const float*)d_in[26];
    const float* ln4_g = (const float*)d_in[27];
    const float* ln4_b = (const float*)d_in[28];
    const float* out_W = (const float*)d_in[29];
    const float* out_b = (const float*)d_in[30];
    (void)in_sizes; (void)n_in; (void)out_size; (void)ws_size;

    float* ws = (float*)d_ws;
    unsigned short* xlb = (unsigned short*)(ws + 0);
    float* xr   = ws + 800000;
    unsigned short* w1t = (unsigned short*)(ws + 2400000);
    unsigned short* w2t = (unsigned short*)(ws + 2727680);
    float* gsum = ws + 2735872;
    float* gcnt = ws + 2736128;
    // edge-phase scratch (aliased over MLP scratch)
    int* bstart = (int*)(ws + 2736192);
    int* bhist  = (int*)(ws + 2736992);
    int* bofs   = (int*)(ws + 2837088);
    int* pairs  = (int*)(ws + 2937184);
    // MLP scratch (valid after bucket_reduce completes)
    float* f1           = ws + 2736192;
    unsigned short* f1b = (unsigned short*)(ws + 4833344);
    float* f2           = ws + 5881920;
    float* f3           = ws + 6406208;
    float* xf           = ws + 6471744;

    hipMemsetAsync(gsum, 0, 320 * sizeof(float), stream);

    node_xform<<<N_NODES / 16, 256, 0, stream>>>(x, W_l, b_l, W_r, b_r, xlb, xr);
    edge_hist<<<HBLK, 256, 0, stream>>>(ei, bhist);
    edge_scan<<<1, 1024, 0, stream>>>(bhist, bofs, bstart);
    edge_scatter<<<HBLK, 256, 0, stream>>>(ei, bofs, pairs);
    castT<<<dim3(10, 256), 256, 0, stream>>>(l1_W, w1t, FEAT, 256);
    castT<<<dim3(1, 64), 256, 0, stream>>>(l2_W, w2t, 256, 64);
    bucket_reduce<<<NBK, 256, 0, stream>>>(pairs, bstart, xlb, xr, att, conv_b,
                                           jk_W, jk_b, batch, gsum, gcnt);
    mfma_gemm_l1<<<dim3(MROWS / 64, 2), 256, 0, stream>>>(
        features, w1t, l1_b, f1, MROWS, 256, FEAT);
    ln_leaky_c256<<<MROWS, 256, 0, stream>>>(f1, f1b, ln1_g, ln1_b);
    mfma_gemm_l2<<<dim3(MROWS / 32, 1), 256, 0, stream>>>(
        f1b, w2t, l2_b, f2, MROWS, 64, 256);
    ln_leaky_c64<<<MROWS / 4, 256, 0, stream>>>(f2, ln2_g, ln2_b);
    l3_ln_leaky<<<MROWS / 32, 256, 0, stream>>>(f2, l3_W, l3_b, ln3_g, ln3_b, f3);
    flat_ln_leaky<<<NB, 256, 0, stream>>>(f3, fl_W, fl_b, ln4_g, ln4_b, xf);
    final_out<<<1, 128, 0, stream>>>(gsum, gcnt, xf, one_hot, out_W, out_b, (float*)d_out);
}

// Round 5
// 632.603 us; speedup vs baseline: 4.4265x; 1.1515x over previous
//
#include <hip/hip_runtime.h>
#include <cstdint>
#include <cstddef>

#define N_NODES 200000
#define N_EDGES 6400000
#define NB      64
#define MROWS   8192     // NB*ROWS
#define FEAT    2560

// edge bucketing: bucket = 256 consecutive dst nodes
#define BSZ   256
#define NBK   782        // ceil(200000/256)
#define EBLK  512        // edge_bucket blocks
#define ETILE 12500      // edges per block (EBLK*ETILE == N_EDGES)
#define BCAP  8960       // per-bucket region capacity (mean 8187, sd ~90)

typedef __attribute__((ext_vector_type(8))) short bf16x8;
typedef __attribute__((ext_vector_type(4))) float f32x4;

__device__ __forceinline__ unsigned short bf16rne(float f) {
    unsigned u = __builtin_bit_cast(unsigned, f);
    u += 0x7fffu + ((u >> 16) & 1u);
    return (unsigned short)(u >> 16);
}

__device__ __forceinline__ void async_cp16(const void* g, void* l) {
    __builtin_amdgcn_global_load_lds(
        (const __attribute__((address_space(1))) unsigned int*)g,
        (__attribute__((address_space(3))) unsigned int*)l, 16, 0, 0);
}

// unpack bf16x6 gather, accumulate one edge into register z/agg
__device__ __forceinline__ void edge_acc(
    uint4 g, const float* xrd, const float* attv, float& z, float* agg)
{
    float xls[6];
    xls[0] = __builtin_bit_cast(float, g.x << 16);
    xls[1] = __builtin_bit_cast(float, g.x & 0xffff0000u);
    xls[2] = __builtin_bit_cast(float, g.y << 16);
    xls[3] = __builtin_bit_cast(float, g.y & 0xffff0000u);
    xls[4] = __builtin_bit_cast(float, g.z << 16);
    xls[5] = __builtin_bit_cast(float, g.z & 0xffff0000u);
    float sc = 0.f;
#pragma unroll
    for (int j = 0; j < 6; j++) {
        float e = xls[j] + xrd[j];
        e = (e >= 0.f) ? e : 0.2f * e;
        sc += attv[j] * e;
    }
    const float p = __expf(sc);
    z += p;
#pragma unroll
    for (int j = 0; j < 6; j++) agg[j] += p * xls[j];
}

// ---------------------------------------------------------------------------
// Workspace layout (4-byte units), edge scratch aliased over MLP scratch:
//   xlb  (bf16[200000][8])   @ 0
//   xr   (f32 [200000][8])   @ 800,000
//   w1t  (bf16[256][2560])   @ 2,400,000
//   w2t  (bf16[64][256])     @ 2,727,680
//   gsum [256] @2,735,872 ; gcnt [64] @2,736,128 ; cursor [782] @2,736,192
//     (memset span: 1102 dw from gsum)
//   union @ 2,737,024:
//     edge: pairs[782*8960] .. 9,743,744   (39.0 MB total)
//     mlp:  f1 f32[8192*256] @2,737,024; f1b bf16 @4,834,176;
//           f2 @5,358,464; f3 @5,882,752 (wait, see launch code offsets)
// ---------------------------------------------------------------------------

// xl (bf16 packed, 16B/node) and xr (f32, stride 8) node transforms.
__global__ __launch_bounds__(256) void node_xform(
    const float* __restrict__ x,
    const float* __restrict__ Wl, const float* __restrict__ bl,
    const float* __restrict__ Wr, const float* __restrict__ br,
    unsigned short* __restrict__ xlb, float* __restrict__ xr)
{
    const int t = threadIdx.x;
    const int l = t & 15;
    const int node = blockIdx.x * 16 + (t >> 4);

    float wl[48], wr[48];
#pragma unroll
    for (int q = 0; q < 12; q++) {
        *(float4*)&wl[q * 4] = *(const float4*)(Wl + 48 * l + 4 * q);
        *(float4*)&wr[q * 4] = *(const float4*)(Wr + 48 * l + 4 * q);
    }
    float xv[8];
    *(float4*)&xv[0] = *(const float4*)(x + (size_t)node * 128 + l * 8);
    *(float4*)&xv[4] = *(const float4*)(x + (size_t)node * 128 + l * 8 + 4);

    float al[6] = {}, ar[6] = {};
#pragma unroll
    for (int i = 0; i < 8; i++) {
#pragma unroll
        for (int j = 0; j < 6; j++) {
            al[j] += xv[i] * wl[i * 6 + j];
            ar[j] += xv[i] * wr[i * 6 + j];
        }
    }
#pragma unroll
    for (int off = 8; off >= 1; off >>= 1) {
#pragma unroll
        for (int j = 0; j < 6; j++) {
            al[j] += __shfl_xor(al[j], off);
            ar[j] += __shfl_xor(ar[j], off);
        }
    }
    if (l == 0) {
        union { unsigned short h[8]; uint4 v; } u;
#pragma unroll
        for (int j = 0; j < 6; j++) u.h[j] = bf16rne(al[j] + bl[j]);
        u.h[6] = 0; u.h[7] = 0;
        *(uint4*)(xlb + (size_t)node * 8) = u.v;
        float4 r0; float2 r1;
        r0.x = ar[0] + br[0]; r0.y = ar[1] + br[1];
        r0.z = ar[2] + br[2]; r0.w = ar[3] + br[3];
        r1.x = ar[4] + br[4]; r1.y = ar[5] + br[5];
        *(float4*)(xr + (size_t)node * 8) = r0;
        *(float2*)(xr + (size_t)node * 8 + 4) = r1;
    }
}

// Fused hist + reserve + scatter. One pass: dst cached in LDS, per-bucket
// space reserved with one global atomicAdd per (block,bucket), then direct
// scatter into fixed-capacity bucket regions. pairs = src<<8 | dst&255.
__global__ __launch_bounds__(256) void edge_bucket(
    const int* __restrict__ ei, int* __restrict__ cursor, int* __restrict__ pairs)
{
    __shared__ int dcache[ETILE];
    __shared__ int h[NBK];
    const int t = threadIdx.x;
    const int base = blockIdx.x * ETILE;
    for (int i = t; i < NBK; i += 256) h[i] = 0;
    __syncthreads();
    for (int i = t; i < ETILE; i += 256) {
        const int d = ei[N_EDGES + base + i];
        dcache[i] = d;
        atomicAdd(&h[d >> 8], 1);
    }
    __syncthreads();
    // reserve global span per bucket; h becomes the scatter cursor
    for (int b = t; b < NBK; b += 256) {
        const int c = h[b];
        int gb = 0;
        if (c > 0) gb = atomicAdd(&cursor[b], c);
        h[b] = b * BCAP + gb;
    }
    __syncthreads();
    for (int i = t; i < ETILE; i += 256) {
        const int d = dcache[i];
        const int s = ei[base + i];
        const int pos = atomicAdd(&h[d >> 8], 1);
        pairs[pos] = (s << 8) | (d & 255);
    }
}

// One block per 256-node bucket. In-LDS counting sort by local dst, then
// thread t owns dst t: walks its contiguous run, accumulates in registers.
// Fused finalize + jk + pooled segment-mean.
__global__ __launch_bounds__(256) void bucket_reduce(
    const int* __restrict__ pairs, const int* __restrict__ cursor,
    const unsigned short* __restrict__ xlb, const float* __restrict__ xr,
    const float* __restrict__ att, const float* __restrict__ conv_b,
    const float* __restrict__ jkW, const float* __restrict__ jkb,
    const int* __restrict__ batch,
    float* __restrict__ gsum, float* __restrict__ gcnt)
{
    __shared__ int sorted[BCAP];
    __shared__ int hist[256];     // histogram, then scatter cursor
    __shared__ int wtot[4];
    const int t = threadIdx.x;
    const int lane = t & 63, wid = t >> 6;
    const int d0 = blockIdx.x * BSZ + t;

    float xrd[6];
    if (d0 < N_NODES) {
        float4 a = *(const float4*)(xr + (size_t)d0 * 8);
        float2 b = *(const float2*)(xr + (size_t)d0 * 8 + 4);
        xrd[0] = a.x; xrd[1] = a.y; xrd[2] = a.z;
        xrd[3] = a.w; xrd[4] = b.x; xrd[5] = b.y;
    } else {
#pragma unroll
        for (int j = 0; j < 6; j++) xrd[j] = 0.f;
    }
    float attv[6];
#pragma unroll
    for (int j = 0; j < 6; j++) attv[j] = att[j];

    float z = 0.f, agg[6] = {};
    const uint4* xl4 = (const uint4*)xlb;
    const int e0 = blockIdx.x * BCAP;
    const int e1 = e0 + cursor[blockIdx.x];

    for (int c0 = e0; c0 < e1; c0 += BCAP) {
        const int rem = e1 - c0;
        const int cnt_chunk = (rem < BCAP) ? rem : BCAP;
        hist[t] = 0;
        __syncthreads();
        for (int i = t; i < cnt_chunk; i += 256)
            atomicAdd(&hist[pairs[c0 + i] & 255], 1);
        __syncthreads();
        // exclusive prefix: wave shfl-scan + cross-wave offsets
        const int h = hist[t];
        int v = h;
#pragma unroll
        for (int d = 1; d < 64; d <<= 1) {
            int o = __shfl_up(v, d);
            if (lane >= d) v += o;
        }
        if (lane == 63) wtot[wid] = v;
        __syncthreads();
        int off = 0;
#pragma unroll
        for (int wv = 0; wv < 3; wv++) if (wv < wid) off += wtot[wv];
        const int my_start = v - h + off;
        const int my_cnt = h;
        __syncthreads();
        hist[t] = my_start;        // becomes scatter cursor
        __syncthreads();
        for (int i = t; i < cnt_chunk; i += 256) {
            const int pv = pairs[c0 + i];
            const int pos = atomicAdd(&hist[pv & 255], 1);
            sorted[pos] = ((unsigned)pv) >> 8;
        }
        __syncthreads();
        // walk my run: 4-wide batched gathers (independent -> pipelined)
        int i = 0;
        for (; i + 4 <= my_cnt; i += 4) {
            const int s0 = sorted[my_start + i];
            const int s1 = sorted[my_start + i + 1];
            const int s2 = sorted[my_start + i + 2];
            const int s3 = sorted[my_start + i + 3];
            const uint4 g0 = xl4[s0], g1 = xl4[s1], g2 = xl4[s2], g3 = xl4[s3];
            edge_acc(g0, xrd, attv, z, agg);
            edge_acc(g1, xrd, attv, z, agg);
            edge_acc(g2, xrd, attv, z, agg);
            edge_acc(g3, xrd, attv, z, agg);
        }
        for (; i < my_cnt; i++) {
            const uint4 g = xl4[sorted[my_start + i]];
            edge_acc(g, xrd, attv, z, agg);
        }
        __syncthreads();           // LDS reused next chunk
    }

    // finalize node d0: self-loop + normalize + leaky + jk + pooled sum
    float hh[4] = {0.f, 0.f, 0.f, 0.f};
    float cw = 0.f;
    int b = 0;
    if (d0 < N_NODES) {
        const uint4 g = xl4[d0];
        float xld[6];
        xld[0] = __builtin_bit_cast(float, g.x << 16);
        xld[1] = __builtin_bit_cast(float, g.x & 0xffff0000u);
        xld[2] = __builtin_bit_cast(float, g.y << 16);
        xld[3] = __builtin_bit_cast(float, g.y & 0xffff0000u);
        xld[4] = __builtin_bit_cast(float, g.z << 16);
        xld[5] = __builtin_bit_cast(float, g.z & 0xffff0000u);
        float sc = 0.f;
#pragma unroll
        for (int j = 0; j < 6; j++) {
            float e = xld[j] + xrd[j];
            e = (e >= 0.f) ? e : 0.2f * e;
            sc += attv[j] * e;
        }
        const float p = __expf(sc);
        const float zz = z + p;
#pragma unroll
        for (int c = 0; c < 4; c++) hh[c] = jkb[c];
#pragma unroll
        for (int j = 0; j < 6; j++) {
            float aj = (agg[j] + p * xld[j]) / zz + conv_b[j];
            aj = (aj >= 0.f) ? aj : 0.01f * aj;
#pragma unroll
            for (int c = 0; c < 4; c++) hh[c] += aj * jkW[j * 4 + c];
        }
        b = batch[d0];
        cw = 1.f;
    }
    const int b0 = __shfl(b, 0);
    if (__all(b == b0)) {
#pragma unroll
        for (int off2 = 32; off2 >= 1; off2 >>= 1) {
#pragma unroll
            for (int c = 0; c < 4; c++) hh[c] += __shfl_xor(hh[c], off2);
            cw += __shfl_xor(cw, off2);
        }
        if (lane == 0 && cw > 0.f) {
#pragma unroll
            for (int c = 0; c < 4; c++) atomicAdd(gsum + b0 * 4 + c, hh[c]);
            atomicAdd(gcnt + b0, cw);
        }
    } else if (cw > 0.f) {
#pragma unroll
        for (int c = 0; c < 4; c++) atomicAdd(gsum + b * 4 + c, hh[c]);
        atomicAdd(gcnt + b, cw);
    }
}

// cast-transpose W[K][N] f32 -> Wt[N][K] bf16
__global__ __launch_bounds__(256) void castT(
    const float* __restrict__ W, unsigned short* __restrict__ Wt, int K, int N)
{
    const int k = blockIdx.x * 256 + threadIdx.x;
    const int n = blockIdx.y;
    if (k < K) Wt[(size_t)n * K + k] = bf16rne(W[(size_t)k * N + n]);
}

// L1 GEMM: C[M,256] = A[M,2560](f32) @ Bt[256,2560](bf16)^T + bias.
// BM=64, BN=128, BK=64; 4 waves 2x2; 16 MFMA/wave/iter; XOR-swizzled LDS.
// Double-buffered: tile i+1's B-async + A-reg loads issued before compute
// on tile i; ONE barrier per iteration; load latency hidden behind MFMA.
__global__ __launch_bounds__(256) void mfma_gemm_l1(
    const float* __restrict__ A, const unsigned short* __restrict__ Bt,
    const float* __restrict__ bias, float* __restrict__ C,
    int M, int N, int K)
{
    __shared__ unsigned short As[2][64 * 64];
    __shared__ unsigned short Bs[2][128 * 64];
    const int t = threadIdx.x;
    const int w = t >> 6, l = t & 63;
    const int l15 = l & 15, quad = l >> 4;
    const int wm = (w & 1) * 32, wn = (w >> 1) * 64;
    const int gm0 = blockIdx.x * 64;
    const int gn0 = blockIdx.y * 128;
    const int r8 = l >> 3;
    const int c8 = (l & 7) ^ r8;
    const int ar = t >> 2;            // A staging: row 0..63
    const int ac0 = (t & 3) * 2;      // A staging: first of 2 chunks

    f32x4 acc[2][4];
#pragma unroll
    for (int mt = 0; mt < 2; mt++)
#pragma unroll
        for (int nt = 0; nt < 4; nt++) acc[mt][nt] = (f32x4){0.f, 0.f, 0.f, 0.f};

    const int niter = K / 64;

    // preload tile 0
#pragma unroll
    for (int c = 0; c < 4; c++) {
        const int j = w * 4 + c;
        async_cp16(Bt + (size_t)(gn0 + j * 8 + r8) * K + c8 * 8, &Bs[0][j * 512]);
    }
    {
        const float* src = A + (size_t)(gm0 + ar) * K + ac0 * 8;
        float4 v0 = *(const float4*)src;
        float4 v1 = *(const float4*)(src + 4);
        float4 v2 = *(const float4*)(src + 8);
        float4 v3 = *(const float4*)(src + 12);
        union { unsigned short h[8]; uint4 u; } p0, p1;
        p0.h[0] = bf16rne(v0.x); p0.h[1] = bf16rne(v0.y);
        p0.h[2] = bf16rne(v0.z); p0.h[3] = bf16rne(v0.w);
        p0.h[4] = bf16rne(v1.x); p0.h[5] = bf16rne(v1.y);
        p0.h[6] = bf16rne(v1.z); p0.h[7] = bf16rne(v1.w);
        p1.h[0] = bf16rne(v2.x); p1.h[1] = bf16rne(v2.y);
        p1.h[2] = bf16rne(v2.z); p1.h[3] = bf16rne(v2.w);
        p1.h[4] = bf16rne(v3.x); p1.h[5] = bf16rne(v3.y);
        p1.h[6] = bf16rne(v3.z); p1.h[7] = bf16rne(v3.w);
        *(uint4*)&As[0][ar * 64 + ((ac0 + 0) ^ (ar & 7)) * 8] = p0.u;
        *(uint4*)&As[0][ar * 64 + ((ac0 + 1) ^ (ar & 7)) * 8] = p1.u;
    }

    int p = 0;
    for (int i = 0; i < niter; i++) {
        __syncthreads();               // buf p ready (drains prev async+lds)
        const bool nxt = (i + 1 < niter);
        float4 v0, v1, v2, v3;
        if (nxt) {
            const int k1 = (i + 1) * 64;
#pragma unroll
            for (int c = 0; c < 4; c++) {
                const int j = w * 4 + c;
                async_cp16(Bt + (size_t)(gn0 + j * 8 + r8) * K + k1 + c8 * 8,
                           &Bs[p ^ 1][j * 512]);
            }
            const float* src = A + (size_t)(gm0 + ar) * K + k1 + ac0 * 8;
            v0 = *(const float4*)src;
            v1 = *(const float4*)(src + 4);
            v2 = *(const float4*)(src + 8);
            v3 = *(const float4*)(src + 12);
        }
        // compute on buffer p
#pragma unroll
        for (int kki = 0; kki < 2; kki++) {
            bf16x8 af[2], bfr[4];
#pragma unroll
            for (int mt = 0; mt < 2; mt++) {
                const int m = wm + mt * 16 + l15;
                af[mt] = *(const bf16x8*)&As[p][m * 64 + (((quad + 4 * kki) ^ (m & 7)) * 8)];
            }
#pragma unroll
            for (int nt = 0; nt < 4; nt++) {
                const int n = wn + nt * 16 + l15;
                bfr[nt] = *(const bf16x8*)&Bs[p][n * 64 + (((quad + 4 * kki) ^ (n & 7)) * 8)];
            }
#pragma unroll
            for (int mt = 0; mt < 2; mt++)
#pragma unroll
                for (int nt = 0; nt < 4; nt++)
                    acc[mt][nt] = __builtin_amdgcn_mfma_f32_16x16x32_bf16(
                        af[mt], bfr[nt], acc[mt][nt], 0, 0, 0);
        }
        if (nxt) {
            union { unsigned short h[8]; uint4 u; } p0, p1;
            p0.h[0] = bf16rne(v0.x); p0.h[1] = bf16rne(v0.y);
            p0.h[2] = bf16rne(v0.z); p0.h[3] = bf16rne(v0.w);
            p0.h[4] = bf16rne(v1.x); p0.h[5] = bf16rne(v1.y);
            p0.h[6] = bf16rne(v1.z); p0.h[7] = bf16rne(v1.w);
            p1.h[0] = bf16rne(v2.x); p1.h[1] = bf16rne(v2.y);
            p1.h[2] = bf16rne(v2.z); p1.h[3] = bf16rne(v2.w);
            p1.h[4] = bf16rne(v3.x); p1.h[5] = bf16rne(v3.y);
            p1.h[6] = bf16rne(v3.z); p1.h[7] = bf16rne(v3.w);
            *(uint4*)&As[p ^ 1][ar * 64 + ((ac0 + 0) ^ (ar & 7)) * 8] = p0.u;
            *(uint4*)&As[p ^ 1][ar * 64 + ((ac0 + 1) ^ (ar & 7)) * 8] = p1.u;
        }
        p ^= 1;
    }
#pragma unroll
    for (int nt = 0; nt < 4; nt++) {
        const int col = gn0 + wn + nt * 16 + l15;
        const float bv = bias[col];
#pragma unroll
        for (int mt = 0; mt < 2; mt++)
#pragma unroll
            for (int rr = 0; rr < 4; rr++) {
                const int row = gm0 + wm + mt * 16 + quad * 4 + rr;
                C[(size_t)row * N + col] = acc[mt][nt][rr] + bv;
            }
    }
}

// L2 GEMM: BM=32 x BN=64, A bf16 via async, Bt bf16.
__global__ __launch_bounds__(256) void mfma_gemm_l2(
    const unsigned short* __restrict__ Ab, const unsigned short* __restrict__ Bt,
    const float* __restrict__ bias, float* __restrict__ C,
    int M, int N, int K)
{
    __shared__ unsigned short As[32 * 64];
    __shared__ unsigned short Bs[64 * 64];
    const int t = threadIdx.x;
    const int w = t >> 6, l = t & 63;
    const int l15 = l & 15, quad = l >> 4;
    const int gm0 = blockIdx.x * 32;
    const int gn0 = blockIdx.y * 64;
    const int r8 = l >> 3;
    const int c8 = (l & 7) ^ r8;

    f32x4 acc[2];
    acc[0] = (f32x4){0.f, 0.f, 0.f, 0.f};
    acc[1] = (f32x4){0.f, 0.f, 0.f, 0.f};

    for (int k0 = 0; k0 < K; k0 += 64) {
#pragma unroll
        for (int c = 0; c < 2; c++) {
            const int j = w * 2 + c;
            async_cp16(Bt + (size_t)(gn0 + j * 8 + r8) * K + k0 + c8 * 8,
                       &Bs[j * 512]);
        }
        async_cp16(Ab + (size_t)(gm0 + w * 8 + r8) * K + k0 + c8 * 8, &As[w * 512]);
        __syncthreads();
#pragma unroll
        for (int kki = 0; kki < 2; kki++) {
            bf16x8 af[2], bfr;
#pragma unroll
            for (int mt = 0; mt < 2; mt++) {
                const int m = mt * 16 + l15;
                af[mt] = *(const bf16x8*)&As[m * 64 + (((quad + 4 * kki) ^ (m & 7)) * 8)];
            }
            const int n = w * 16 + l15;
            bfr = *(const bf16x8*)&Bs[n * 64 + (((quad + 4 * kki) ^ (n & 7)) * 8)];
#pragma unroll
            for (int mt = 0; mt < 2; mt++)
                acc[mt] = __builtin_amdgcn_mfma_f32_16x16x32_bf16(
                    af[mt], bfr, acc[mt], 0, 0, 0);
        }
        __syncthreads();
    }
    const int col = gn0 + w * 16 + l15;
    const float bv = bias[col];
#pragma unroll
    for (int mt = 0; mt < 2; mt++)
#pragma unroll
        for (int rr = 0; rr < 4; rr++) {
            const int row = gm0 + mt * 16 + quad * 4 + rr;
            C[(size_t)row * N + col] = acc[mt][rr] + bv;
        }
}

// LayerNorm(C=256) + leaky(0.01), f32 in -> bf16 out. One block per row.
__global__ __launch_bounds__(256) void ln_leaky_c256(
    const float* __restrict__ f, unsigned short* __restrict__ out,
    const float* __restrict__ g, const float* __restrict__ b)
{
    const int row = blockIdx.x;
    const int t = threadIdx.x;
    float v = f[(size_t)row * 256 + t];
    float s = v, s2 = v * v;
#pragma unroll
    for (int off = 32; off >= 1; off >>= 1) {
        s += __shfl_xor(s, off);
        s2 += __shfl_xor(s2, off);
    }
    __shared__ float ws[4], ws2[4];
    const int wid = t >> 6, lane = t & 63;
    if (lane == 0) { ws[wid] = s; ws2[wid] = s2; }
    __syncthreads();
    const float S = ws[0] + ws[1] + ws[2] + ws[3];
    const float S2 = ws2[0] + ws2[1] + ws2[2] + ws2[3];
    const float mu = S * (1.0f / 256.0f);
    const float var = S2 * (1.0f / 256.0f) - mu * mu;
    float y = (v - mu) * rsqrtf(var + 1e-5f) * g[t] + b[t];
    y = (y >= 0.f) ? y : 0.01f * y;
    out[(size_t)row * 256 + t] = bf16rne(y);
}

// In-place LayerNorm(C=64) + leaky(0.01). One wave per row, 4 rows/block.
__global__ __launch_bounds__(256) void ln_leaky_c64(
    float* __restrict__ f, const float* __restrict__ g, const float* __restrict__ b)
{
    const int wid = threadIdx.x >> 6, lane = threadIdx.x & 63;
    const int row = blockIdx.x * 4 + wid;
    float v = f[(size_t)row * 64 + lane];
    float s = v, s2 = v * v;
#pragma unroll
    for (int off = 32; off >= 1; off >>= 1) {
        s += __shfl_xor(s, off);
        s2 += __shfl_xor(s2, off);
    }
    const float mu = s * (1.0f / 64.0f);
    const float var = s2 * (1.0f / 64.0f) - mu * mu;
    float y = (v - mu) * rsqrtf(var + 1e-5f) * g[lane] + b[lane];
    f[(size_t)row * 64 + lane] = (y >= 0.f) ? y : 0.01f * y;
}

// f3 = leaky(LN(f2 @ W3 + b3)).  8 threads per row.
__global__ __launch_bounds__(256) void l3_ln_leaky(
    const float* __restrict__ f2, const float* __restrict__ W3,
    const float* __restrict__ b3,
    const float* __restrict__ g, const float* __restrict__ b,
    float* __restrict__ f3)
{
    __shared__ float sW[64 * 8];
    const int t = threadIdx.x;
    sW[t] = W3[t]; sW[t + 256] = W3[t + 256];
    __syncthreads();
    const int row = blockIdx.x * 32 + (t >> 3);
    const int c = t & 7;
    float acc = b3[c];
    const float* fr = f2 + (size_t)row * 64;
#pragma unroll 8
    for (int k = 0; k < 64; k++) acc += fr[k] * sW[k * 8 + c];
    float s = acc, s2 = acc * acc;
#pragma unroll
    for (int off = 4; off >= 1; off >>= 1) {
        s += __shfl_xor(s, off);
        s2 += __shfl_xor(s2, off);
    }
    const float mu = s * (1.0f / 8.0f);
    const float var = s2 * (1.0f / 8.0f) - mu * mu;
    float y = (acc - mu) * rsqrtf(var + 1e-5f) * g[c] + b[c];
    f3[(size_t)row * 8 + c] = (y >= 0.f) ? y : 0.01f * y;
}

// xf = leaky(LN(flat @ fl_W + fl_b)). One block per graph.
__global__ __launch_bounds__(256) void flat_ln_leaky(
    const float* __restrict__ f3, const float* __restrict__ W,
    const float* __restrict__ bb,
    const float* __restrict__ g, const float* __restrict__ b,
    float* __restrict__ xf)
{
    __shared__ float sf[1024];
    __shared__ float sp[8][32];
    const int t = threadIdx.x;
    const int gb = blockIdx.x;
    *(float4*)&sf[t * 4] = *(const float4*)(f3 + (size_t)gb * 1024 + t * 4);
    __syncthreads();
    const int c = t & 31, part = t >> 5;
    float acc = 0.f;
    for (int k = part * 128; k < part * 128 + 128; k++) acc += sf[k] * W[k * 32 + c];
    sp[part][c] = acc;
    __syncthreads();
    if (t < 32) {
        float v = bb[t];
#pragma unroll
        for (int p = 0; p < 8; p++) v += sp[p][t];
        float s = v, s2 = v * v;
#pragma unroll
        for (int off = 16; off >= 1; off >>= 1) {
            s += __shfl_xor(s, off);
            s2 += __shfl_xor(s2, off);
        }
        const float mu = s * (1.0f / 32.0f);
        const float var = s2 * (1.0f / 32.0f) - mu * mu;
        float y = (v - mu) * rsqrtf(var + 1e-5f) * g[t] + b[t];
        xf[gb * 32 + t] = (y >= 0.f) ? y : 0.01f * y;
    }
}

// out[b,o] = cat(gsum/cnt, xf, one_hot) @ out_W + out_b
__global__ __launch_bounds__(128) void final_out(
    const float* __restrict__ gsum, const float* __restrict__ gcnt,
    const float* __restrict__ xf, const float* __restrict__ onehot,
    const float* __restrict__ Wo, const float* __restrict__ bo,
    float* __restrict__ out)
{
    const int t = threadIdx.x;
    const int gb = t >> 1, o = t & 1;
    float cnt = gcnt[gb];
    cnt = (cnt > 1.f) ? cnt : 1.f;
    float acc = bo[o];
#pragma unroll
    for (int j = 0; j < 4; j++)  acc += (gsum[gb * 4 + j] / cnt) * Wo[j * 2 + o];
#pragma unroll
    for (int j = 0; j < 32; j++) acc += xf[gb * 32 + j] * Wo[(4 + j) * 2 + o];
#pragma unroll
    for (int j = 0; j < 20; j++) acc += onehot[gb * 20 + j] * Wo[(36 + j) * 2 + o];
    out[t] = acc;
}

extern "C" void kernel_launch(void* const* d_in, const int* in_sizes, int n_in,
                              void* d_out, int out_size, void* d_ws, size_t ws_size,
                              hipStream_t stream)
{
    const float* x        = (const float*)d_in[0];
    const int*   ei       = (const int*)d_in[1];
    const int*   batch    = (const int*)d_in[2];
    const float* features = (const float*)d_in[3];
    const float* one_hot  = (const float*)d_in[4];
    const float* W_l   = (const float*)d_in[5];
    const float* b_l   = (const float*)d_in[6];
    const float* W_r   = (const float*)d_in[7];
    const float* b_r   = (const float*)d_in[8];
    const float* att   = (const float*)d_in[9];
    const float* conv_b = (const float*)d_in[10];
    const float* jk_W  = (const float*)d_in[11];
    const float* jk_b  = (const float*)d_in[12];
    const float* l1_W  = (const float*)d_in[13];
    const float* l1_b  = (const float*)d_in[14];
    const float* ln1_g = (const float*)d_in[15];
    const float* ln1_b = (const float*)d_in[16];
    const float* l2_W  = (const float*)d_in[17];
    const float* l2_b  = (const float*)d_in[18];
    const float* ln2_g = (const float*)d_in[19];
    const float* ln2_b = (const float*)d_in[20];
    const float* l3_W  = (const float*)d_in[21];
    const float* l3_b  = (const float*)d_in[22];
    const float* ln3_g = (const float*)d_in[23];
    const float* ln3_b = (const float*)d_in[24];
    const float* fl_W  = (const float*)d_in[25];
    const float* fl_b  = (const float*)d_in[26];
    const float* ln4_g = (const float*)d_in[27];
    const float* ln4_b = (const float*)d_in[28];
    const float* out_W = (const float*)d_in[29];
    const float* out_b = (const float*)d_in[30];
    (void)in_sizes; (void)n_in; (void)out_size; (void)ws_size;

    float* ws = (float*)d_ws;
    unsigned short* xlb = (unsigned short*)(ws + 0);
    float* xr   = ws + 800000;
    unsigned short* w1t = (unsigned short*)(ws + 2400000);
    unsigned short* w2t = (unsigned short*)(ws + 2727680);
    float* gsum   = ws + 2735872;
    float* gcnt   = ws + 2736128;
    int*   cursor = (int*)(ws + 2736192);          // [782]
    // union @ 2,737,024
    int* pairs = (int*)(ws + 2737024);             // 782*8960 = 7,006,720 ints
    float* f1           = ws + 2737024;            // 8192*256
    unsigned short* f1b = (unsigned short*)(ws + 4834176);
    float* f2           = ws + 5358464;            // 8192*64
    float* f3           = ws + 5882752;            // 8192*8
    float* xf           = ws + 5948288;            // 64*32

    // zero gsum+gcnt+cursor (contiguous 1102 dwords)
    hipMemsetAsync(gsum, 0, 1102 * sizeof(float), stream);

    node_xform<<<N_NODES / 16, 256, 0, stream>>>(x, W_l, b_l, W_r, b_r, xlb, xr);
    edge_bucket<<<EBLK, 256, 0, stream>>>(ei, cursor, pairs);
    castT<<<dim3(10, 256), 256, 0, stream>>>(l1_W, w1t, FEAT, 256);
    castT<<<dim3(1, 64), 256, 0, stream>>>(l2_W, w2t, 256, 64);
    bucket_reduce<<<NBK, 256, 0, stream>>>(pairs, cursor, xlb, xr, att, conv_b,
                                           jk_W, jk_b, batch, gsum, gcnt);
    mfma_gemm_l1<<<dim3(MROWS / 64, 2), 256, 0, stream>>>(
        features, w1t, l1_b, f1, MROWS, 256, FEAT);
    ln_leaky_c256<<<MROWS, 256, 0, stream>>>(f1, f1b, ln1_g, ln1_b);
    mfma_gemm_l2<<<dim3(MROWS / 32, 1), 256, 0, stream>>>(
        f1b, w2t, l2_b, f2, MROWS, 64, 256);
    ln_leaky_c64<<<MROWS / 4, 256, 0, stream>>>(f2, ln2_g, ln2_b);
    l3_ln_leaky<<<MROWS / 32, 256, 0, stream>>>(f2, l3_W, l3_b, ln3_g, ln3_b, f3);
    flat_ln_leaky<<<NB, 256, 0, stream>>>(f3, fl_W, fl_b, ln4_g, ln4_b, xf);
    final_out<<<1, 128, 0, stream>>>(gsum, gcnt, xf, one_hot, out_W, out_b, (float*)d_out);
}